// Round 1
// baseline (15499.207 us; speedup 1.0000x reference)
//
#include <hip/hip_runtime.h>

#define Hd 512
#define Bd 512
#define Vd 128
#define Sd 256

typedef _Float16 half8 __attribute__((ext_vector_type(8)));
typedef _Float16 half4v __attribute__((ext_vector_type(4)));
typedef float float4v __attribute__((ext_vector_type(4)));

__device__ __forceinline__ float sigf(float v) { return 1.0f / (1.0f + __expf(-v)); }
__device__ __forceinline__ float tanhfast(float v) { return 1.0f - 2.0f / (__expf(2.0f * v) + 1.0f); }

__device__ __forceinline__ void load_lds16(const void* g, void* l) {
  __builtin_amdgcn_global_load_lds(
      (const __attribute__((address_space(1))) unsigned int*)g,
      (__attribute__((address_space(3))) unsigned int*)l, 16, 0, 0);
}

// wxt[dir][v][n] = Wx[g][k][v] + bx[g*H+k] + bh[g*H+k], n = (k<<2)|g. fp32.
__global__ __launch_bounds__(256) void prep_wxt(
    const float* __restrict__ WxF, const float* __restrict__ bxF, const float* __restrict__ bhF,
    const float* __restrict__ WxB, const float* __restrict__ bxB, const float* __restrict__ bhB,
    float* __restrict__ wxt) {
  int e = blockIdx.x * 256 + threadIdx.x;   // 0..524287
  int n = e & 2047;
  int v = (e >> 11) & 127;
  int dir = e >> 18;
  int k = n >> 2, g = n & 3;
  const float* Wx = dir ? WxB : WxF;
  const float* bx = dir ? bxB : bxF;
  const float* bh = dir ? bhB : bhF;
  int gk = g * Hd + k;
  wxt[e] = Wx[gk * Vd + v] + bx[gk] + bh[gk];
}

// whr[dir][n][hc] f16 = Wh_dir[g][k][hc], n = (k<<2)|g
__global__ __launch_bounds__(256) void prep_wh16(
    const float* __restrict__ WhF, const float* __restrict__ WhB, _Float16* __restrict__ whr) {
  int e = blockIdx.x * 256 + threadIdx.x;   // 0..2097151
  int hc = e & 511;
  int n = (e >> 9) & 2047;
  int dir = e >> 20;
  int k = n >> 2, g = n & 3;
  const float* Wh = dir ? WhB : WhF;
  whr[e] = (_Float16)Wh[(g * Hd + k) * Hd + hc];
}

// wfc16[dir][v][hc] f16 = Wfc[v][dir*512+hc]
__global__ __launch_bounds__(256) void prep_wfc16(
    const float* __restrict__ Wfc, _Float16* __restrict__ wfc16) {
  int e = blockIdx.x * 256 + threadIdx.x;   // 0..131071
  int hc = e & 511;
  int v = (e >> 9) & 127;
  int dir = e >> 16;
  wfc16[e] = (_Float16)Wfc[v * 1024 + dir * 512 + hc];
}

// xT[t][b] = x[b][t]
__global__ __launch_bounds__(256) void prep_xT(const int* __restrict__ x, int* __restrict__ xT) {
  int e = blockIdx.x * 256 + threadIdx.x;   // 0..131071
  int t = e >> 9, b = e & 511;
  xT[e] = x[b * Sd + t];
}

__global__ __launch_bounds__(256) void init_zero(float* __restrict__ p) {
  int e = blockIdx.x * 256 + threadIdx.x;
  float4 z; z.x = 0.f; z.y = 0.f; z.z = 0.f; z.w = 0.f;
  ((float4*)p)[e] = z;
}

__global__ __launch_bounds__(256) void init_out(const float* __restrict__ bfc,
                                                float* __restrict__ out) {
  int e = blockIdx.x * 256 + threadIdx.x;
  int v0 = (e & 31) * 4;
  ((float4*)out)[e] = *(const float4*)&bfc[v0];
}

// ---------------------------------------------------------------------------
// Persistent BiLSTM kernel. 256 blocks x 256 threads, cooperative.
// block: dir = bid>>7; loc = bid&127; mt = loc&7 (64 b-rows); nt = loc>>3 (128 n-rows).
// LDS: WhT [128][512] f16, xor-swizzled per 16B slot (131072 B)  — resident all steps
//      GT  [128][68]  f16 epilogue transpose                      (17408 B)
#define SMEM_BYTES (131072 + 17408)

__global__ __launch_bounds__(256, 1) void bilstm_persist(
    const float* __restrict__ wxt, const int* __restrict__ xT,
    const _Float16* __restrict__ whr, const _Float16* __restrict__ wfc16,
    _Float16* __restrict__ hbuf, unsigned* __restrict__ flags,
    float* __restrict__ out) {
  extern __shared__ char smem[];
  _Float16* GT = (_Float16*)(smem + 131072);

  const int tid = threadIdx.x;
  const int lane = tid & 63;
  const int w = tid >> 6;
  const int bid = blockIdx.x;
  const int dir = bid >> 7;
  const int loc = bid & 127;
  const int mt = loc & 7;
  const int nt = loc >> 3;
  const int b0 = mt * 64;

  // ---- prologue: Wh slice -> LDS, swizzled via pre-swizzled GLOBAL source ----
  // LDS slot e (n=e>>6, cs=e&63) gets G[n][cs ^ (n&7)]; reads XOR again -> identity.
  {
    const char* wsrc = (const char*)(whr + ((size_t)(dir * 2048 + nt * 128)) * Hd);
#pragma unroll
    for (int i = 0; i < 32; ++i) {
      int e = i * 256 + tid;
      int n = e >> 6, cs = e & 63;
      load_lds16(wsrc + (size_t)n * 1024 + (size_t)(((cs ^ (n & 7)) * 16)),
                 (char*)smem + (size_t)e * 16);
    }
  }

  const int l15 = lane & 15;
  const int kq = lane >> 4;                 // 0..3
  const int wm0 = (w & 1) * 32;             // m-half within 64
  const int wn0 = (w >> 1) * 64;            // n-half within 128

  int arow[2];                               // A (h) global offsets, halves
#pragma unroll
  for (int mi = 0; mi < 2; ++mi) arow[mi] = (b0 + wm0 + mi * 16 + l15) * Hd + kq * 8;
  int brow[4], bxor[4];                      // B (Wh) LDS row byte base + swizzle
#pragma unroll
  for (int ni = 0; ni < 4; ++ni) {
    int n = wn0 + ni * 16 + l15;
    brow[ni] = n * 1024;
    bxor[ni] = n & 7;
  }

  float creg[8];                             // c-state lives in registers
#pragma unroll
  for (int i = 0; i < 8; ++i) creg[i] = 0.f;

  const int bl = tid & 63;                   // epilogue: b within tile
  const int kh = tid >> 6;                   // epilogue: 8-k group

  __syncthreads();                           // WhT ready (drains global_load_lds)

  for (int s = 0; s <= Sd; ++s) {
    const int ph = s & 1;
    const _Float16* hprev = hbuf + (size_t)ph * (2 * Bd * Hd);
    _Float16* hnext = hbuf + (size_t)(ph ^ 1) * (2 * Bd * Hd);

    if (s < Sd) {
      const _Float16* A = hprev + (size_t)dir * (Bd * Hd);
      float4v acc[2][4];
#pragma unroll
      for (int mi = 0; mi < 2; ++mi)
#pragma unroll
        for (int ni = 0; ni < 4; ++ni) acc[mi][ni] = (float4v)0.f;

#pragma unroll
      for (int kc = 0; kc < 16; ++kc) {
        half8 af[2], bf[4];
#pragma unroll
        for (int mi = 0; mi < 2; ++mi)
          af[mi] = *(const half8*)(A + arow[mi] + kc * 32);
#pragma unroll
        for (int ni = 0; ni < 4; ++ni)
          bf[ni] = *(const half8*)((const char*)smem + brow[ni] +
                                   (((kc * 4 + kq) ^ bxor[ni]) * 16));
#pragma unroll
        for (int mi = 0; mi < 2; ++mi)
#pragma unroll
          for (int ni = 0; ni < 4; ++ni)
            acc[mi][ni] = __builtin_amdgcn_mfma_f32_16x16x32_f16(af[mi], bf[ni], acc[mi][ni], 0, 0, 0);
      }

      // transpose preacts to LDS (f16)
#pragma unroll
      for (int mi = 0; mi < 2; ++mi) {
        int m = wm0 + mi * 16 + kq * 4;
#pragma unroll
        for (int ni = 0; ni < 4; ++ni) {
          int n = wn0 + ni * 16 + l15;
          half4v hv4;
          hv4[0] = (_Float16)acc[mi][ni][0];
          hv4[1] = (_Float16)acc[mi][ni][1];
          hv4[2] = (_Float16)acc[mi][ni][2];
          hv4[3] = (_Float16)acc[mi][ni][3];
          *(half4v*)&GT[n * 68 + m] = hv4;
        }
      }
      __syncthreads();

      // pointwise: thread (bl, kh) owns b = b0+bl, k = nt*32 + kh*8 .. +8
      const int t = dir ? (Sd - 1 - s) : s;
      const int b = b0 + bl;
      const int xv = xT[t * Bd + b];
      const float* wrow = wxt + ((size_t)(dir * Vd + xv)) * 2048 + nt * 128 + kh * 32;
      half8 hv;
#pragma unroll
      for (int kl = 0; kl < 8; ++kl) {
        int kloc = kh * 8 + kl;
        float4 wv = *(const float4*)&wrow[kl * 4];
        float g0 = (float)GT[(kloc * 4 + 0) * 68 + bl] + wv.x;
        float g1 = (float)GT[(kloc * 4 + 1) * 68 + bl] + wv.y;
        float g2 = (float)GT[(kloc * 4 + 2) * 68 + bl] + wv.z;
        float g3 = (float)GT[(kloc * 4 + 3) * 68 + bl] + wv.w;
        float gi = sigf(g0), gf = sigf(g1), go = sigf(g2), gg = tanhfast(g3);
        float cn = gf * creg[kl] + gi * gg;
        creg[kl] = cn;
        hv[kl] = (_Float16)(go * tanhfast(cn));
      }
      *(half8*)(hnext + (size_t)dir * (Bd * Hd) + (size_t)b * Hd + nt * 32 + kh * 8) = hv;
    }

    // ---- FC of previous step's h: 128 tasks on alternating block halves ----
    if (s > 0 && ((s & 1) ? (bid < 128) : (bid >= 128))) {
      const int fid = bid & 127;
      const int dfc = fid >> 6;
      const int rem = fid & 63;
      const int bt = rem >> 3;          // 8 x 64 b-rows
      const int vt = rem & 7;           // 8 x 16 v
      const int tf = dfc ? (Sd - s) : (s - 1);
      const _Float16* Afc = hprev + (size_t)dfc * (Bd * Hd) +
                            (size_t)(bt * 64 + w * 16 + l15) * Hd + kq * 8;
      const _Float16* Bfc = wfc16 + (size_t)dfc * (Vd * Hd) +
                            (size_t)(vt * 16 + l15) * Hd + kq * 8;
      float4v fa = (float4v)0.f;
#pragma unroll
      for (int kc = 0; kc < 16; ++kc)
        fa = __builtin_amdgcn_mfma_f32_16x16x32_f16(*(const half8*)(Afc + kc * 32),
                                                    *(const half8*)(Bfc + kc * 32), fa, 0, 0, 0);
      const int v = vt * 16 + l15;
      const int bb = bt * 64 + w * 16 + kq * 4;
      float* op = out + ((size_t)bb * Sd + tf) * Vd + v;
#pragma unroll
      for (int r2 = 0; r2 < 4; ++r2) op[(size_t)r2 * (Sd * Vd)] += fa[r2];
    }

    // ---- grid barrier: flag-array, one store per block, 256 parallel spins ----
    __syncthreads();
    __threadfence();
    if (tid == 0)
      __hip_atomic_store(&flags[bid * 32], (unsigned)(s + 1), __ATOMIC_RELEASE,
                         __HIP_MEMORY_SCOPE_AGENT);
    {
      const unsigned tgt = (unsigned)(s + 1);
      unsigned* myf = &flags[tid * 32];
      while (__hip_atomic_load(myf, __ATOMIC_RELAXED, __HIP_MEMORY_SCOPE_AGENT) < tgt)
        __builtin_amdgcn_s_sleep(1);
    }
    __threadfence();
    __syncthreads();
  }
}

extern "C" void kernel_launch(void* const* d_in, const int* in_sizes, int n_in,
                              void* d_out, int out_size, void* d_ws, size_t ws_size,
                              hipStream_t stream) {
  (void)in_sizes; (void)n_in; (void)out_size; (void)ws_size;
  const int* x      = (const int*)d_in[0];
  const float* WxF  = (const float*)d_in[1];
  const float* WhF  = (const float*)d_in[2];
  const float* bxF  = (const float*)d_in[3];
  const float* bhF  = (const float*)d_in[4];
  const float* WxB  = (const float*)d_in[5];
  const float* WhB  = (const float*)d_in[6];
  const float* bxB  = (const float*)d_in[7];
  const float* bhB  = (const float*)d_in[8];
  const float* Wfc  = (const float*)d_in[9];
  const float* bfc  = (const float*)d_in[10];
  float* out = (float*)d_out;

  // ws (float units):
  //   wxt    @ 0        : 524288
  //   hbuf   @ 524288   : 524288   (f16, 2 phases x 2 dir x 512 x 512)
  //   flags  @ 1048576  : 8192     (unsigned, 256 x 32)
  //   wh16   @ 1056768  : 1048576  (f16, 2 dir x 2048 x 512)
  //   wfc16  @ 2105344  : 65536    (f16, 2 dir x 128 x 512)
  //   xT     @ 2170880  : 131072   (int, 256 x 512)
  float* ws = (float*)d_ws;
  float* wxt        = ws;
  _Float16* hbuf    = (_Float16*)(ws + 524288);
  unsigned* flags   = (unsigned*)(ws + 1048576);
  _Float16* wh16    = (_Float16*)(ws + 1056768);
  _Float16* wfc16   = (_Float16*)(ws + 2105344);
  int* xT           = (int*)(ws + 2170880);

  prep_wxt<<<2048, 256, 0, stream>>>(WxF, bxF, bhF, WxB, bxB, bhB, wxt);
  prep_wh16<<<8192, 256, 0, stream>>>(WhF, WhB, wh16);
  prep_wfc16<<<512, 256, 0, stream>>>(Wfc, wfc16);
  prep_xT<<<512, 256, 0, stream>>>(x, xT);
  init_zero<<<520, 256, 0, stream>>>(ws + 524288);   // hbuf + flags
  init_out<<<16384, 256, 0, stream>>>(bfc, out);

  static bool attr_set = false;
  if (!attr_set) {
    hipFuncSetAttribute((const void*)bilstm_persist,
                        hipFuncAttributeMaxDynamicSharedMemorySize, SMEM_BYTES);
    attr_set = true;
  }
  void* kargs[] = {(void*)&wxt, (void*)&xT, (void*)&wh16, (void*)&wfc16,
                   (void*)&hbuf, (void*)&flags, (void*)&out};
  if (hipLaunchCooperativeKernel((const void*)bilstm_persist, dim3(256), dim3(256),
                                 kargs, SMEM_BYTES, stream) != hipSuccess) {
    // fallback: plain launch — 148 KB LDS forces 1 block/CU, 256 blocks on 256 CUs
    bilstm_persist<<<dim3(256), dim3(256), SMEM_BYTES, stream>>>(
        wxt, xT, wh16, wfc16, hbuf, flags, out);
  }
}

// Round 2
// 4346.730 us; speedup vs baseline: 3.5657x; 3.5657x over previous
//
#include <hip/hip_runtime.h>

#define Hd 512
#define Bd 512
#define Vd 128
#define Sd 256

typedef _Float16 half8 __attribute__((ext_vector_type(8)));
typedef _Float16 half4v __attribute__((ext_vector_type(4)));
typedef float float4v __attribute__((ext_vector_type(4)));

__device__ __forceinline__ float sigf(float v) { return 1.0f / (1.0f + __expf(-v)); }
__device__ __forceinline__ float tanhfast(float v) { return 1.0f - 2.0f / (__expf(2.0f * v) + 1.0f); }

__device__ __forceinline__ void load_lds16(const void* g, void* l) {
  __builtin_amdgcn_global_load_lds(
      (const __attribute__((address_space(1))) unsigned int*)g,
      (__attribute__((address_space(3))) unsigned int*)l, 16, 0, 0);
}

// Agent-coherent (cross-XCD visible) 16B h load/store as 2x relaxed 8B atomics.
// Relaxed atomics emit single cache-bypassing ops — NO fences, NO L2 flush.
__device__ __forceinline__ half8 loadh8_coh(const _Float16* p) {
  union { unsigned long long u[2]; half8 h; } cv;
  cv.u[0] = __hip_atomic_load((const unsigned long long*)p, __ATOMIC_RELAXED,
                              __HIP_MEMORY_SCOPE_AGENT);
  cv.u[1] = __hip_atomic_load((const unsigned long long*)p + 1, __ATOMIC_RELAXED,
                              __HIP_MEMORY_SCOPE_AGENT);
  return cv.h;
}
__device__ __forceinline__ void storeh8_coh(_Float16* p, half8 v) {
  union { unsigned long long u[2]; half8 h; } cv;
  cv.h = v;
  __hip_atomic_store((unsigned long long*)p, cv.u[0], __ATOMIC_RELAXED,
                     __HIP_MEMORY_SCOPE_AGENT);
  __hip_atomic_store((unsigned long long*)p + 1, cv.u[1], __ATOMIC_RELAXED,
                     __HIP_MEMORY_SCOPE_AGENT);
}

// wxt[dir][v][n] = Wx[g][k][v] + bx[g*H+k] + bh[g*H+k], n = (k<<2)|g. fp32.
__global__ __launch_bounds__(256) void prep_wxt(
    const float* __restrict__ WxF, const float* __restrict__ bxF, const float* __restrict__ bhF,
    const float* __restrict__ WxB, const float* __restrict__ bxB, const float* __restrict__ bhB,
    float* __restrict__ wxt) {
  int e = blockIdx.x * 256 + threadIdx.x;   // 0..524287
  int n = e & 2047;
  int v = (e >> 11) & 127;
  int dir = e >> 18;
  int k = n >> 2, g = n & 3;
  const float* Wx = dir ? WxB : WxF;
  const float* bx = dir ? bxB : bxF;
  const float* bh = dir ? bhB : bhF;
  int gk = g * Hd + k;
  wxt[e] = Wx[gk * Vd + v] + bx[gk] + bh[gk];
}

// whr[dir][n][hc] f16 = Wh_dir[g][k][hc], n = (k<<2)|g
__global__ __launch_bounds__(256) void prep_wh16(
    const float* __restrict__ WhF, const float* __restrict__ WhB, _Float16* __restrict__ whr) {
  int e = blockIdx.x * 256 + threadIdx.x;   // 0..2097151
  int hc = e & 511;
  int n = (e >> 9) & 2047;
  int dir = e >> 20;
  int k = n >> 2, g = n & 3;
  const float* Wh = dir ? WhB : WhF;
  whr[e] = (_Float16)Wh[(g * Hd + k) * Hd + hc];
}

// wfc16[dir][v][hc] f16 = Wfc[v][dir*512+hc]
__global__ __launch_bounds__(256) void prep_wfc16(
    const float* __restrict__ Wfc, _Float16* __restrict__ wfc16) {
  int e = blockIdx.x * 256 + threadIdx.x;   // 0..131071
  int hc = e & 511;
  int v = (e >> 9) & 127;
  int dir = e >> 16;
  wfc16[e] = (_Float16)Wfc[v * 1024 + dir * 512 + hc];
}

// xT[t][b] = x[b][t]
__global__ __launch_bounds__(256) void prep_xT(const int* __restrict__ x, int* __restrict__ xT) {
  int e = blockIdx.x * 256 + threadIdx.x;   // 0..131071
  int t = e >> 9, b = e & 511;
  xT[e] = x[b * Sd + t];
}

__global__ __launch_bounds__(256) void init_zero(float* __restrict__ p) {
  int e = blockIdx.x * 256 + threadIdx.x;
  float4 z; z.x = 0.f; z.y = 0.f; z.z = 0.f; z.w = 0.f;
  ((float4*)p)[e] = z;
}

__global__ __launch_bounds__(256) void init_out(const float* __restrict__ bfc,
                                                float* __restrict__ out) {
  int e = blockIdx.x * 256 + threadIdx.x;
  int v0 = (e & 31) * 4;
  ((float4*)out)[e] = *(const float4*)&bfc[v0];
}

// ---------------------------------------------------------------------------
// Persistent BiLSTM. 256 blocks x 256 threads.
// group = bid>>4 (16 groups of 16 blocks); nt = bid&15; dir = grp>>3; mt = grp&7.
// Each group owns h[dir][mt*64 .. mt*64+64) — groups are fully independent;
// barriers are 16-block group barriers (relaxed agent atomics, no fences).
// LDS: WhT [128][512] f16 xor-swizzled (131072 B) resident, GT [128][68] (17408 B).
#define SMEM_BYTES (131072 + 17408)

#define ISSUE_CHUNK(DST, C)                                                    \
  _Pragma("unroll") for (int mi = 0; mi < 2; ++mi)                             \
  _Pragma("unroll") for (int j = 0; j < 4; ++j)                                \
      DST[mi][j] = loadh8_coh(Ab + arow[mi] + ((C) * 4 + j) * 32);

#define COMPUTE_CHUNK(SRC, C)                                                  \
  _Pragma("unroll") for (int j = 0; j < 4; ++j) {                              \
    half8 bf[4];                                                               \
    _Pragma("unroll") for (int ni = 0; ni < 4; ++ni)                           \
        bf[ni] = *(const half8*)((const char*)smem + brow[ni] +                \
                                 (((((C) * 4 + j) * 4 + kq) ^ bxor[ni]) * 16));\
    _Pragma("unroll") for (int mi = 0; mi < 2; ++mi)                           \
    _Pragma("unroll") for (int ni = 0; ni < 4; ++ni)                           \
        acc[mi][ni] = __builtin_amdgcn_mfma_f32_16x16x32_f16(                  \
            SRC[mi][j], bf[ni], acc[mi][ni], 0, 0, 0);                         \
  }

__global__ __launch_bounds__(256, 1) void bilstm_persist(
    const float* __restrict__ wxt, const int* __restrict__ xT,
    const _Float16* __restrict__ whr, const _Float16* __restrict__ wfc16,
    _Float16* __restrict__ hbuf, unsigned* __restrict__ flags,
    float* __restrict__ out) {
  extern __shared__ char smem[];
  _Float16* GT = (_Float16*)(smem + 131072);

  const int tid = threadIdx.x;
  const int lane = tid & 63;
  const int w = tid >> 6;
  const int bid = blockIdx.x;
  const int grp = bid >> 4;       // 0..15
  const int nt = bid & 15;        // 0..15
  const int dir = grp >> 3;
  const int mt = grp & 7;
  const int b0 = mt * 64;

  // ---- prologue: Wh slice -> LDS, swizzled via pre-swizzled GLOBAL source ----
  {
    const char* wsrc = (const char*)(whr + ((size_t)(dir * 2048 + nt * 128)) * Hd);
#pragma unroll
    for (int i = 0; i < 32; ++i) {
      int e = i * 256 + tid;
      int n = e >> 6, cs = e & 63;
      load_lds16(wsrc + (size_t)n * 1024 + (size_t)(((cs ^ (n & 7)) * 16)),
                 (char*)smem + (size_t)e * 16);
    }
  }

  const int l15 = lane & 15;
  const int kq = lane >> 4;                 // 0..3
  const int wm0 = (w & 1) * 32;             // m-half within 64
  const int wn0 = (w >> 1) * 64;            // n-half within 128

  int arow[2];
#pragma unroll
  for (int mi = 0; mi < 2; ++mi) arow[mi] = (b0 + wm0 + mi * 16 + l15) * Hd + kq * 8;
  int brow[4], bxor[4];
#pragma unroll
  for (int ni = 0; ni < 4; ++ni) {
    int n = wn0 + ni * 16 + l15;
    brow[ni] = n * 1024;
    bxor[ni] = n & 7;
  }

  float creg[8];
#pragma unroll
  for (int i = 0; i < 8; ++i) creg[i] = 0.f;

  const int bl = tid & 63;                   // epilogue: b within tile
  const int kh = tid >> 6;                   // epilogue: 8-k group (0..3)
  const int fcn = nt & 7;                    // FC v-tile

  __syncthreads();                           // WhT ready (drains global_load_lds)

  for (int s = 0; s <= Sd; ++s) {
    const int ph = s & 1;
    const _Float16* hprev_d = hbuf + (size_t)ph * (2 * Bd * Hd) + (size_t)dir * (Bd * Hd);
    _Float16* hnext_d = hbuf + (size_t)(ph ^ 1) * (2 * Bd * Hd) + (size_t)dir * (Bd * Hd);

    if (s < Sd) {
      const _Float16* Ab = hprev_d;
      float4v acc[2][4];
#pragma unroll
      for (int mi = 0; mi < 2; ++mi)
#pragma unroll
        for (int ni = 0; ni < 4; ++ni) acc[mi][ni] = (float4v)0.f;

      half8 aX[2][4], aY[2][4];
      ISSUE_CHUNK(aX, 0)
      ISSUE_CHUNK(aY, 1)
      COMPUTE_CHUNK(aX, 0)
      ISSUE_CHUNK(aX, 2)
      COMPUTE_CHUNK(aY, 1)
      ISSUE_CHUNK(aY, 3)
      COMPUTE_CHUNK(aX, 2)
      COMPUTE_CHUNK(aY, 3)

      // transpose preacts to LDS (f16)
#pragma unroll
      for (int mi = 0; mi < 2; ++mi) {
        int m = wm0 + mi * 16 + kq * 4;
#pragma unroll
        for (int ni = 0; ni < 4; ++ni) {
          int n = wn0 + ni * 16 + l15;
          half4v hv4;
          hv4[0] = (_Float16)acc[mi][ni][0];
          hv4[1] = (_Float16)acc[mi][ni][1];
          hv4[2] = (_Float16)acc[mi][ni][2];
          hv4[3] = (_Float16)acc[mi][ni][3];
          *(half4v*)&GT[n * 68 + m] = hv4;
        }
      }
      __syncthreads();

      // pointwise: thread (bl, kh) owns b = b0+bl, k = nt*32 + kh*8 .. +8
      const int t = dir ? (Sd - 1 - s) : s;
      const int b = b0 + bl;
      const int xv = xT[t * Bd + b];
      const float* wrow = wxt + ((size_t)(dir * Vd + xv)) * 2048 + nt * 128 + kh * 32;
      half8 hv;
#pragma unroll
      for (int kl = 0; kl < 8; ++kl) {
        int kloc = kh * 8 + kl;
        float4 wv = *(const float4*)&wrow[kl * 4];
        float g0 = (float)GT[(kloc * 4 + 0) * 68 + bl] + wv.x;
        float g1 = (float)GT[(kloc * 4 + 1) * 68 + bl] + wv.y;
        float g2 = (float)GT[(kloc * 4 + 2) * 68 + bl] + wv.z;
        float g3 = (float)GT[(kloc * 4 + 3) * 68 + bl] + wv.w;
        float gi = sigf(g0), gf = sigf(g1), go = sigf(g2), gg = tanhfast(g3);
        float cn = gf * creg[kl] + gi * gg;
        creg[kl] = cn;
        hv[kl] = (_Float16)(go * tanhfast(cn));
      }
      storeh8_coh(hnext_d + (size_t)b * Hd + nt * 32 + kh * 8, hv);
      __syncthreads();   // GT reads done before next step overwrites (and pre-barrier drain)
    }

    // ---- FC of previous step's h: in-group, 8 blocks x (64b x 16v), alternate ----
    const bool fc_act = (s & 1) ? (nt < 8) : (nt >= 8);
    if (s > 0 && fc_act) {
      const _Float16* Afc = hprev_d + (size_t)(b0 + w * 16 + l15) * Hd + kq * 8;
      const _Float16* Bfc = wfc16 + (size_t)dir * (Vd * Hd) +
                            (size_t)(fcn * 16 + l15) * Hd + kq * 8;
      half8 aF[8], aG[8];
#pragma unroll
      for (int k = 0; k < 8; ++k) aF[k] = loadh8_coh(Afc + k * 32);
#pragma unroll
      for (int k = 0; k < 8; ++k) aG[k] = loadh8_coh(Afc + (8 + k) * 32);
      float4v fa = (float4v)0.f;
#pragma unroll
      for (int k = 0; k < 8; ++k)
        fa = __builtin_amdgcn_mfma_f32_16x16x32_f16(aF[k], *(const half8*)(Bfc + k * 32),
                                                    fa, 0, 0, 0);
#pragma unroll
      for (int k = 0; k < 8; ++k)
        fa = __builtin_amdgcn_mfma_f32_16x16x32_f16(aG[k], *(const half8*)(Bfc + (8 + k) * 32),
                                                    fa, 0, 0, 0);
      const int tf = dir ? (Sd - s) : (s - 1);
      const int v = fcn * 16 + l15;
      const int bb = b0 + w * 16 + kq * 4;
      float* op = out + ((size_t)bb * Sd + tf) * Vd + v;
#pragma unroll
      for (int r2 = 0; r2 < 4; ++r2)
        unsafeAtomicAdd(op + (size_t)r2 * (Sd * Vd), fa[r2]);
    }

    if (s == Sd) break;

    // ---- group barrier: 16 blocks. __syncthreads drains vmcnt(0) in every wave,
    // so all h-stores are at the coherent point before the flag is published.
    __syncthreads();
    if (tid == 0)
      __hip_atomic_store(&flags[bid * 32], (unsigned)(s + 1), __ATOMIC_RELAXED,
                         __HIP_MEMORY_SCOPE_AGENT);
    if (tid < 16) {
      unsigned* f = flags + (grp * 16 + tid) * 32;
      while (__hip_atomic_load(f, __ATOMIC_RELAXED, __HIP_MEMORY_SCOPE_AGENT) <
             (unsigned)(s + 1))
        __builtin_amdgcn_s_sleep(1);
    }
    __syncthreads();
  }
}

extern "C" void kernel_launch(void* const* d_in, const int* in_sizes, int n_in,
                              void* d_out, int out_size, void* d_ws, size_t ws_size,
                              hipStream_t stream) {
  (void)in_sizes; (void)n_in; (void)out_size; (void)ws_size;
  const int* x      = (const int*)d_in[0];
  const float* WxF  = (const float*)d_in[1];
  const float* WhF  = (const float*)d_in[2];
  const float* bxF  = (const float*)d_in[3];
  const float* bhF  = (const float*)d_in[4];
  const float* WxB  = (const float*)d_in[5];
  const float* WhB  = (const float*)d_in[6];
  const float* bxB  = (const float*)d_in[7];
  const float* bhB  = (const float*)d_in[8];
  const float* Wfc  = (const float*)d_in[9];
  const float* bfc  = (const float*)d_in[10];
  float* out = (float*)d_out;

  // ws (float units):
  //   wxt    @ 0        : 524288
  //   hbuf   @ 524288   : 524288   (f16, 2 phases x 2 dir x 512 x 512)
  //   flags  @ 1048576  : 8192     (unsigned, 256 x 32)
  //   wh16   @ 1056768  : 1048576  (f16, 2 dir x 2048 x 512)
  //   wfc16  @ 2105344  : 65536    (f16, 2 dir x 128 x 512)
  //   xT     @ 2170880  : 131072   (int, 256 x 512)
  float* ws = (float*)d_ws;
  float* wxt        = ws;
  _Float16* hbuf    = (_Float16*)(ws + 524288);
  unsigned* flags   = (unsigned*)(ws + 1048576);
  _Float16* wh16    = (_Float16*)(ws + 1056768);
  _Float16* wfc16   = (_Float16*)(ws + 2105344);
  int* xT           = (int*)(ws + 2170880);

  prep_wxt<<<2048, 256, 0, stream>>>(WxF, bxF, bhF, WxB, bxB, bhB, wxt);
  prep_wh16<<<8192, 256, 0, stream>>>(WhF, WhB, wh16);
  prep_wfc16<<<512, 256, 0, stream>>>(Wfc, wfc16);
  prep_xT<<<512, 256, 0, stream>>>(x, xT);
  init_zero<<<520, 256, 0, stream>>>(ws + 524288);   // hbuf + flags
  init_out<<<16384, 256, 0, stream>>>(bfc, out);

  static bool attr_set = false;
  if (!attr_set) {
    hipFuncSetAttribute((const void*)bilstm_persist,
                        hipFuncAttributeMaxDynamicSharedMemorySize, SMEM_BYTES);
    attr_set = true;
  }
  void* kargs[] = {(void*)&wxt, (void*)&xT, (void*)&wh16, (void*)&wfc16,
                   (void*)&hbuf, (void*)&flags, (void*)&out};
  if (hipLaunchCooperativeKernel((const void*)bilstm_persist, dim3(256), dim3(256),
                                 kargs, SMEM_BYTES, stream) != hipSuccess) {
    // fallback: plain launch — 148 KB LDS forces 1 block/CU, 256 blocks on 256 CUs
    bilstm_persist<<<dim3(256), dim3(256), SMEM_BYTES, stream>>>(
        wxt, xT, wh16, wfc16, hbuf, flags, out);
  }
}

// Round 4
// 2234.193 us; speedup vs baseline: 6.9373x; 1.9455x over previous
//
#include <hip/hip_runtime.h>

#define Hd 512
#define Bd 512
#define Vd 128
#define Sd 256

typedef _Float16 half8 __attribute__((ext_vector_type(8)));
typedef _Float16 half4v __attribute__((ext_vector_type(4)));
typedef float float4v __attribute__((ext_vector_type(4)));
typedef unsigned int uint4v __attribute__((ext_vector_type(4)));

__device__ __forceinline__ float sigf(float v) { return 1.0f / (1.0f + __expf(-v)); }
__device__ __forceinline__ float tanhfast(float v) { return 1.0f - 2.0f / (__expf(2.0f * v) + 1.0f); }

__device__ __forceinline__ void load_lds16(const void* g, void* l) {
  __builtin_amdgcn_global_load_lds(
      (const __attribute__((address_space(1))) unsigned int*)g,
      (__attribute__((address_space(3))) unsigned int*)l, 16, 0, 0);
}

#if __has_builtin(__builtin_amdgcn_raw_buffer_load_b128) && \
    __has_builtin(__builtin_amdgcn_make_buffer_rsrc)
#define USE_BUFLD 1
#else
#define USE_BUFLD 0
#endif

// Coherent (L1+L2-bypass via sc0 sc1 -> reads coherent point) 16B fragment load.
#if USE_BUFLD
__device__ __forceinline__ half8 load_frag(__amdgpu_buffer_rsrc_t rs,
                                           const _Float16* base, unsigned voff) {
  uint4v d = __builtin_amdgcn_raw_buffer_load_b128(rs, voff, 0, 17 /*sc0|sc1*/);
  union { uint4v u; half8 h; } cv; cv.u = d;
  return cv.h;
}
#else
typedef int __amdgpu_buffer_rsrc_dummy_t;
#define __amdgpu_buffer_rsrc_t __amdgpu_buffer_rsrc_dummy_t
__device__ __forceinline__ half8 load_frag(__amdgpu_buffer_rsrc_t rs,
                                           const _Float16* base, unsigned voff) {
  (void)rs;
  const char* p = (const char*)base + voff;
  union { unsigned long long u[2]; half8 h; } cv;
  cv.u[0] = __hip_atomic_load((const unsigned long long*)p, __ATOMIC_RELAXED,
                              __HIP_MEMORY_SCOPE_AGENT);
  cv.u[1] = __hip_atomic_load((const unsigned long long*)(p + 8), __ATOMIC_RELAXED,
                              __HIP_MEMORY_SCOPE_AGENT);
  return cv.h;
}
#endif

// Proven write-through h store (relaxed agent atomics, contiguous 16B pair).
__device__ __forceinline__ void storeh8_coh(_Float16* base, unsigned voff, half8 v) {
  char* p = (char*)base + voff;
  union { unsigned long long u[2]; half8 h; } cv;
  cv.h = v;
  __hip_atomic_store((unsigned long long*)p, cv.u[0], __ATOMIC_RELAXED,
                     __HIP_MEMORY_SCOPE_AGENT);
  __hip_atomic_store((unsigned long long*)(p + 8), cv.u[1], __ATOMIC_RELAXED,
                     __HIP_MEMORY_SCOPE_AGENT);
}

// wxt[dir][v][n] = Wx[g][k][v] + bx[g*H+k] + bh[g*H+k], n = (k<<2)|g. fp32.
__global__ __launch_bounds__(256) void prep_wxt(
    const float* __restrict__ WxF, const float* __restrict__ bxF, const float* __restrict__ bhF,
    const float* __restrict__ WxB, const float* __restrict__ bxB, const float* __restrict__ bhB,
    float* __restrict__ wxt) {
  int e = blockIdx.x * 256 + threadIdx.x;   // 0..524287
  int n = e & 2047;
  int v = (e >> 11) & 127;
  int dir = e >> 18;
  int k = n >> 2, g = n & 3;
  const float* Wx = dir ? WxB : WxF;
  const float* bx = dir ? bxB : bxF;
  const float* bh = dir ? bhB : bhF;
  int gk = g * Hd + k;
  wxt[e] = Wx[gk * Vd + v] + bx[gk] + bh[gk];
}

// whr[dir][n][hc] f16 = Wh_dir[g][k][hc], n = (k<<2)|g
__global__ __launch_bounds__(256) void prep_wh16(
    const float* __restrict__ WhF, const float* __restrict__ WhB, _Float16* __restrict__ whr) {
  int e = blockIdx.x * 256 + threadIdx.x;   // 0..2097151
  int hc = e & 511;
  int n = (e >> 9) & 2047;
  int dir = e >> 20;
  int k = n >> 2, g = n & 3;
  const float* Wh = dir ? WhB : WhF;
  whr[e] = (_Float16)Wh[(g * Hd + k) * Hd + hc];
}

// wfc16[dir][v][hc] f16 = Wfc[v][dir*512+hc]
__global__ __launch_bounds__(256) void prep_wfc16(
    const float* __restrict__ Wfc, _Float16* __restrict__ wfc16) {
  int e = blockIdx.x * 256 + threadIdx.x;   // 0..131071
  int hc = e & 511;
  int v = (e >> 9) & 127;
  int dir = e >> 16;
  wfc16[e] = (_Float16)Wfc[v * 1024 + dir * 512 + hc];
}

// xT[t][b] = x[b][t]
__global__ __launch_bounds__(256) void prep_xT(const int* __restrict__ x, int* __restrict__ xT) {
  int e = blockIdx.x * 256 + threadIdx.x;   // 0..131071
  int t = e >> 9, b = e & 511;
  xT[e] = x[b * Sd + t];
}

__global__ __launch_bounds__(256) void init_zero(float* __restrict__ p) {
  int e = blockIdx.x * 256 + threadIdx.x;
  float4 z; z.x = 0.f; z.y = 0.f; z.z = 0.f; z.w = 0.f;
  ((float4*)p)[e] = z;
}

__global__ __launch_bounds__(256) void init_out(const float* __restrict__ bfc,
                                                float* __restrict__ out) {
  int e = blockIdx.x * 256 + threadIdx.x;
  int v0 = (e & 31) * 4;
  ((float4*)out)[e] = *(const float4*)&bfc[v0];
}

// ---------------------------------------------------------------------------
// Persistent BiLSTM. 256 blocks x 256 threads.
// group = bid>>4 (16 groups of 16 blocks); nt = bid&15; dir = grp>>3; mt = grp&7.
// h layout (per phase-dir block, f16): [bt=b>>4][c=k>>3][r=b&15][e=k&7]
//   byte(b,k) = (b>>4)*16384 + (k>>3)*256 + (b&15)*16 + (k&7)*2
//   -> one MFMA A-fragment = contiguous 16B/lane; one wave load = 1KB contiguous.
// 4 h phases (reuse distance 4 steps) so flag-publish can precede FC safely.
// LDS: WhT [128][512] f16 xor-swizzled (131072 B) resident, GT [128][68] (17408 B).
#define SMEM_BYTES (131072 + 17408)

#define ISSUE_C(D, C)                                                          \
  _Pragma("unroll") for (int mi = 0; mi < 2; ++mi)                             \
  _Pragma("unroll") for (int j = 0; j < 4; ++j)                                \
      D[mi][j] = load_frag(rs, hbuf, aoff[mi] + (unsigned)(((C) * 4 + j) * 1024));

#define COMPUTE_C(D, C)                                                        \
  _Pragma("unroll") for (int j = 0; j < 4; ++j) {                              \
    half8 bf[4];                                                               \
    _Pragma("unroll") for (int ni = 0; ni < 4; ++ni)                           \
        bf[ni] = *(const half8*)((const char*)smem + brow[ni] +                \
                                 (((((C) * 4 + j) * 4 + kq) ^ bxor[ni]) * 16));\
    _Pragma("unroll") for (int mi = 0; mi < 2; ++mi)                           \
    _Pragma("unroll") for (int ni = 0; ni < 4; ++ni)                           \
        acc[mi][ni] = __builtin_amdgcn_mfma_f32_16x16x32_f16(                  \
            D[mi][j], bf[ni], acc[mi][ni], 0, 0, 0);                           \
  }

__global__ __launch_bounds__(256, 1) void bilstm_persist(
    const float* __restrict__ wxt, const int* __restrict__ xT,
    const _Float16* __restrict__ whr, const _Float16* __restrict__ wfc16,
    _Float16* __restrict__ hbuf, unsigned* __restrict__ flags,
    float* __restrict__ out) {
  extern __shared__ char smem[];
  _Float16* GT = (_Float16*)(smem + 131072);

  const int tid = threadIdx.x;
  const int lane = tid & 63;
  const int w = tid >> 6;
  const int bid = blockIdx.x;
  const int grp = bid >> 4;       // 0..15
  const int nt = bid & 15;        // 0..15
  const int dir = grp >> 3;
  const int mt = grp & 7;
  const int b0 = mt * 64;

  // ---- prologue: Wh slice -> LDS, swizzled via pre-swizzled GLOBAL source ----
  {
    const char* wsrc = (const char*)(whr + ((size_t)(dir * 2048 + nt * 128)) * Hd);
#pragma unroll
    for (int i = 0; i < 32; ++i) {
      int e = i * 256 + tid;
      int n = e >> 6, cs = e & 63;
      load_lds16(wsrc + (size_t)n * 1024 + (size_t)(((cs ^ (n & 7)) * 16)),
                 (char*)smem + (size_t)e * 16);
    }
  }

  const int l15 = lane & 15;
  const int kq = lane >> 4;                 // 0..3
  const int wm0 = (w & 1) * 32;             // m-half within 64
  const int wn0 = (w >> 1) * 64;            // n-half within 128

#if USE_BUFLD
  const __amdgpu_buffer_rsrc_t rs = __builtin_amdgcn_make_buffer_rsrc(
      (void*)hbuf, (short)0, (int)(4u * 2u * 524288u), 0x00020000);
#else
  const __amdgpu_buffer_rsrc_t rs = 0;
#endif

  // A-fragment per-lane offsets (phase-independent part)
  const unsigned bt_base = (unsigned)((b0 >> 4) + (w & 1) * 2);
  unsigned aoff_lane[2];
#pragma unroll
  for (int mi = 0; mi < 2; ++mi)
    aoff_lane[mi] = (bt_base + mi) * 16384u + kq * 256u + l15 * 16u;

  int brow[4], bxor[4];
#pragma unroll
  for (int ni = 0; ni < 4; ++ni) {
    int n = wn0 + ni * 16 + l15;
    brow[ni] = n * 1024;
    bxor[ni] = n & 7;
  }

  float creg[8];
#pragma unroll
  for (int i = 0; i < 8; ++i) creg[i] = 0.f;

  const int bl = tid & 63;                   // epilogue: b within tile
  const int kh = tid >> 6;                   // epilogue: 8-k group (0..3)
  const int fcn = nt & 7;                    // FC v-tile
  // epilogue h-store offset (phase-independent part)
  const unsigned soff_lane = (unsigned)(((b0 + bl) >> 4)) * 16384u +
                             (unsigned)(nt * 4 + kh) * 256u + (unsigned)(bl & 15) * 16u;
  // FC per-lane offset (phase-independent part)
  const unsigned fcoff_lane = (unsigned)((b0 >> 4) + w) * 16384u + kq * 256u + l15 * 16u;

  __syncthreads();                           // WhT ready (drains global_load_lds)

  for (int s = 0; s <= Sd; ++s) {
    const unsigned ph = (unsigned)(s & 3);
    const unsigned abase = (ph * 2u + (unsigned)dir) * 524288u;          // read phase
    const unsigned nbase = (((unsigned)(s + 1) & 3u) * 2u + (unsigned)dir) * 524288u;

    if (s < Sd) {
      unsigned aoff[2];
      aoff[0] = abase + aoff_lane[0];
      aoff[1] = abase + aoff_lane[1];
      float4v acc[2][4];
#pragma unroll
      for (int mi = 0; mi < 2; ++mi)
#pragma unroll
        for (int ni = 0; ni < 4; ++ni) acc[mi][ni] = (float4v)0.f;

      half8 a0[2][4], a1[2][4], a2[2][4], a3[2][4];
      ISSUE_C(a0, 0)
      ISSUE_C(a1, 1)
      ISSUE_C(a2, 2)
      COMPUTE_C(a0, 0)
      ISSUE_C(a3, 3)
      COMPUTE_C(a1, 1)
      COMPUTE_C(a2, 2)
      COMPUTE_C(a3, 3)

      // transpose preacts to LDS (f16)
#pragma unroll
      for (int mi = 0; mi < 2; ++mi) {
        int m = wm0 + mi * 16 + kq * 4;
#pragma unroll
        for (int ni = 0; ni < 4; ++ni) {
          int n = wn0 + ni * 16 + l15;
          half4v hv4;
          hv4[0] = (_Float16)acc[mi][ni][0];
          hv4[1] = (_Float16)acc[mi][ni][1];
          hv4[2] = (_Float16)acc[mi][ni][2];
          hv4[3] = (_Float16)acc[mi][ni][3];
          *(half4v*)&GT[n * 68 + m] = hv4;
        }
      }
      __syncthreads();

      // pointwise: thread (bl, kh) owns b = b0+bl, k = nt*32 + kh*8 .. +8
      const int t = dir ? (Sd - 1 - s) : s;
      const int b = b0 + bl;
      const int xv = xT[t * Bd + b];
      const float* wrow = wxt + ((size_t)(dir * Vd + xv)) * 2048 + nt * 128 + kh * 32;
      half8 hv;
#pragma unroll
      for (int kl = 0; kl < 8; ++kl) {
        int kloc = kh * 8 + kl;
        float4 wv = *(const float4*)&wrow[kl * 4];
        float g0 = (float)GT[(kloc * 4 + 0) * 68 + bl] + wv.x;
        float g1 = (float)GT[(kloc * 4 + 1) * 68 + bl] + wv.y;
        float g2 = (float)GT[(kloc * 4 + 2) * 68 + bl] + wv.z;
        float g3 = (float)GT[(kloc * 4 + 3) * 68 + bl] + wv.w;
        float gi = sigf(g0), gf = sigf(g1), go = sigf(g2), gg = tanhfast(g3);
        float cn = gf * creg[kl] + gi * gg;
        creg[kl] = cn;
        hv[kl] = (_Float16)(go * tanhfast(cn));
      }
      storeh8_coh(hbuf, nbase + soff_lane, hv);

      // Drain h-stores (syncthreads waits vmcnt(0) in each wave), then publish
      // EARLY so the group barrier cost overlaps with the FC below.
      __syncthreads();
      if (tid == 0)
        __hip_atomic_store(&flags[bid * 32], (unsigned)(s + 1), __ATOMIC_RELAXED,
                           __HIP_MEMORY_SCOPE_AGENT);
    }

    // ---- FC of previous step's h: in-group, 8 blocks x (64b x 16v), alternate.
    // Reads phase ph (own group rows). Safe vs overwrite at step s+3: writers
    // need this block's flag >= s+3, published only after this FC completes.
    const bool fc_act = (s & 1) ? (nt < 8) : (nt >= 8);
    if (s > 0 && fc_act) {
      const unsigned fo = abase + fcoff_lane;
      const _Float16* Bfc = wfc16 + (size_t)dir * (Vd * Hd) +
                            (size_t)(fcn * 16 + l15) * Hd + kq * 8;
      half8 aF[16];
#pragma unroll
      for (int k = 0; k < 16; ++k) aF[k] = load_frag(rs, hbuf, fo + k * 1024u);
      float4v fa = (float4v)0.f;
#pragma unroll
      for (int k = 0; k < 16; ++k)
        fa = __builtin_amdgcn_mfma_f32_16x16x32_f16(aF[k], *(const half8*)(Bfc + k * 32),
                                                    fa, 0, 0, 0);
      const int tf = dir ? (Sd - s) : (s - 1);
      const int v = fcn * 16 + l15;
      const int bb = b0 + w * 16 + kq * 4;
      float* op = out + ((size_t)bb * Sd + tf) * Vd + v;
#pragma unroll
      for (int r2 = 0; r2 < 4; ++r2)
        unsafeAtomicAdd(op + (size_t)r2 * (Sd * Vd), fa[r2]);
    }

    if (s == Sd) break;

    // ---- group barrier: 16 blocks, poll own-group flags ----
    if (tid < 16) {
      unsigned* f = flags + (grp * 16 + tid) * 32;
      while (__hip_atomic_load(f, __ATOMIC_RELAXED, __HIP_MEMORY_SCOPE_AGENT) <
             (unsigned)(s + 1))
        __builtin_amdgcn_s_sleep(1);
    }
    __syncthreads();
  }
}

extern "C" void kernel_launch(void* const* d_in, const int* in_sizes, int n_in,
                              void* d_out, int out_size, void* d_ws, size_t ws_size,
                              hipStream_t stream) {
  (void)in_sizes; (void)n_in; (void)out_size; (void)ws_size;
  const int* x      = (const int*)d_in[0];
  const float* WxF  = (const float*)d_in[1];
  const float* WhF  = (const float*)d_in[2];
  const float* bxF  = (const float*)d_in[3];
  const float* bhF  = (const float*)d_in[4];
  const float* WxB  = (const float*)d_in[5];
  const float* WhB  = (const float*)d_in[6];
  const float* bxB  = (const float*)d_in[7];
  const float* bhB  = (const float*)d_in[8];
  const float* Wfc  = (const float*)d_in[9];
  const float* bfc  = (const float*)d_in[10];
  float* out = (float*)d_out;

  // ws (float units):
  //   wxt    @ 0        : 524288
  //   hbuf   @ 524288   : 1048576  (f16, 4 phases x 2 dir x 512 x 512)
  //   flags  @ 1572864  : 8192     (unsigned, 256 x 32)
  //   wh16   @ 1581056  : 1048576  (f16, 2 dir x 2048 x 512)
  //   wfc16  @ 2629632  : 65536    (f16, 2 dir x 128 x 512)
  //   xT     @ 2695168  : 131072   (int, 256 x 512)
  float* ws = (float*)d_ws;
  float* wxt        = ws;
  _Float16* hbuf    = (_Float16*)(ws + 524288);
  unsigned* flags   = (unsigned*)(ws + 1572864);
  _Float16* wh16    = (_Float16*)(ws + 1581056);
  _Float16* wfc16   = (_Float16*)(ws + 2629632);
  int* xT           = (int*)(ws + 2695168);

  prep_wxt<<<2048, 256, 0, stream>>>(WxF, bxF, bhF, WxB, bxB, bhB, wxt);
  prep_wh16<<<8192, 256, 0, stream>>>(WhF, WhB, wh16);
  prep_wfc16<<<512, 256, 0, stream>>>(Wfc, wfc16);
  prep_xT<<<512, 256, 0, stream>>>(x, xT);
  init_zero<<<256, 256, 0, stream>>>(ws + 524288);    // h phase 0 (1 MB)
  init_zero<<<8, 256, 0, stream>>>(ws + 1572864);     // flags
  init_out<<<16384, 256, 0, stream>>>(bfc, out);

  static bool attr_set = false;
  if (!attr_set) {
    (void)hipFuncSetAttribute((const void*)bilstm_persist,
                              hipFuncAttributeMaxDynamicSharedMemorySize, SMEM_BYTES);
    attr_set = true;
  }
  void* kargs[] = {(void*)&wxt, (void*)&xT, (void*)&wh16, (void*)&wfc16,
                   (void*)&hbuf, (void*)&flags, (void*)&out};
  if (hipLaunchCooperativeKernel((const void*)bilstm_persist, dim3(256), dim3(256),
                                 kargs, SMEM_BYTES, stream) != hipSuccess) {
    // fallback: plain launch — 148 KB LDS forces 1 block/CU, 256 blocks on 256 CUs
    bilstm_persist<<<dim3(256), dim3(256), SMEM_BYTES, stream>>>(
        wxt, xT, wh16, wfc16, hbuf, flags, out);
  }
}

// Round 5
// 1756.276 us; speedup vs baseline: 8.8250x; 1.2721x over previous
//
#include <hip/hip_runtime.h>

#define Hd 512
#define Bd 512
#define Vd 128
#define Sd 256

typedef _Float16 half8 __attribute__((ext_vector_type(8)));
typedef _Float16 half4v __attribute__((ext_vector_type(4)));
typedef float float4v __attribute__((ext_vector_type(4)));
typedef unsigned int uint4v __attribute__((ext_vector_type(4)));

__device__ __forceinline__ float sigf(float v) { return 1.0f / (1.0f + __expf(-v)); }
__device__ __forceinline__ float tanhfast(float v) { return 1.0f - 2.0f / (__expf(2.0f * v) + 1.0f); }

__device__ __forceinline__ void load_lds16(const void* g, void* l) {
  __builtin_amdgcn_global_load_lds(
      (const __attribute__((address_space(1))) unsigned int*)g,
      (__attribute__((address_space(3))) unsigned int*)l, 16, 0, 0);
}

#if __has_builtin(__builtin_amdgcn_raw_buffer_load_b128) && \
    __has_builtin(__builtin_amdgcn_make_buffer_rsrc)
#define USE_BUFLD 1
#else
#define USE_BUFLD 0
#endif

// Coherent (L1+L2-bypass via sc0 sc1 -> reads coherent point) 16B fragment load.
#if USE_BUFLD
__device__ __forceinline__ half8 load_frag(__amdgpu_buffer_rsrc_t rs,
                                           const _Float16* base, unsigned voff) {
  uint4v d = __builtin_amdgcn_raw_buffer_load_b128(rs, voff, 0, 17 /*sc0|sc1*/);
  union { uint4v u; half8 h; } cv; cv.u = d;
  return cv.h;
}
#else
typedef int __amdgpu_buffer_rsrc_dummy_t;
#define __amdgpu_buffer_rsrc_t __amdgpu_buffer_rsrc_dummy_t
__device__ __forceinline__ half8 load_frag(__amdgpu_buffer_rsrc_t rs,
                                           const _Float16* base, unsigned voff) {
  (void)rs;
  const char* p = (const char*)base + voff;
  union { unsigned long long u[2]; half8 h; } cv;
  cv.u[0] = __hip_atomic_load((const unsigned long long*)p, __ATOMIC_RELAXED,
                              __HIP_MEMORY_SCOPE_AGENT);
  cv.u[1] = __hip_atomic_load((const unsigned long long*)(p + 8), __ATOMIC_RELAXED,
                              __HIP_MEMORY_SCOPE_AGENT);
  return cv.h;
#endif
#if !USE_BUFLD
}
#endif

// Proven write-through h store (relaxed agent atomic, contiguous 8B).
__device__ __forceinline__ void storeh4_coh(_Float16* base, unsigned voff, half4v v) {
  char* p = (char*)base + voff;
  union { unsigned long long u; half4v h; } cv;
  cv.h = v;
  __hip_atomic_store((unsigned long long*)p, cv.u, __ATOMIC_RELAXED,
                     __HIP_MEMORY_SCOPE_AGENT);
}

// wxt[dir][v][n] = Wx[g][k][v] + bx[g*H+k] + bh[g*H+k], n = (k<<2)|g. fp32.
__global__ __launch_bounds__(256) void prep_wxt(
    const float* __restrict__ WxF, const float* __restrict__ bxF, const float* __restrict__ bhF,
    const float* __restrict__ WxB, const float* __restrict__ bxB, const float* __restrict__ bhB,
    float* __restrict__ wxt) {
  int e = blockIdx.x * 256 + threadIdx.x;   // 0..524287
  int n = e & 2047;
  int v = (e >> 11) & 127;
  int dir = e >> 18;
  int k = n >> 2, g = n & 3;
  const float* Wx = dir ? WxB : WxF;
  const float* bx = dir ? bxB : bxF;
  const float* bh = dir ? bhB : bhF;
  int gk = g * Hd + k;
  wxt[e] = Wx[gk * Vd + v] + bx[gk] + bh[gk];
}

// whr[dir][n][hc] f16 = Wh_dir[g][k][hc], n = (k<<2)|g
__global__ __launch_bounds__(256) void prep_wh16(
    const float* __restrict__ WhF, const float* __restrict__ WhB, _Float16* __restrict__ whr) {
  int e = blockIdx.x * 256 + threadIdx.x;   // 0..2097151
  int hc = e & 511;
  int n = (e >> 9) & 2047;
  int dir = e >> 20;
  int k = n >> 2, g = n & 3;
  const float* Wh = dir ? WhB : WhF;
  whr[e] = (_Float16)Wh[(g * Hd + k) * Hd + hc];
}

// wfc16[dir][v][hc] f16 = Wfc[v][dir*512+hc]
__global__ __launch_bounds__(256) void prep_wfc16(
    const float* __restrict__ Wfc, _Float16* __restrict__ wfc16) {
  int e = blockIdx.x * 256 + threadIdx.x;   // 0..131071
  int hc = e & 511;
  int v = (e >> 9) & 127;
  int dir = e >> 16;
  wfc16[e] = (_Float16)Wfc[v * 1024 + dir * 512 + hc];
}

// xT[t][b] = x[b][t]
__global__ __launch_bounds__(256) void prep_xT(const int* __restrict__ x, int* __restrict__ xT) {
  int e = blockIdx.x * 256 + threadIdx.x;   // 0..131071
  int t = e >> 9, b = e & 511;
  xT[e] = x[b * Sd + t];
}

__global__ __launch_bounds__(256) void init_zero(float* __restrict__ p) {
  int e = blockIdx.x * 256 + threadIdx.x;
  float4 z; z.x = 0.f; z.y = 0.f; z.z = 0.f; z.w = 0.f;
  ((float4*)p)[e] = z;
}

__global__ __launch_bounds__(256) void init_out(const float* __restrict__ bfc,
                                                float* __restrict__ out) {
  int e = blockIdx.x * 256 + threadIdx.x;
  int v0 = (e & 31) * 4;
  ((float4*)out)[e] = *(const float4*)&bfc[v0];
}

// ---------------------------------------------------------------------------
// Persistent BiLSTM. 256 blocks x 512 threads (8 waves, 2-way K-split).
// group = bid>>4 (16 groups of 16 blocks); nt = bid&15; dir = grp>>3; mt = grp&7.
// Wave w: ks = w>>2 (K half: kc in [ks*8, ks*8+8)); wl = w&3 -> 32m x 64n subtile.
// h layout (per phase-dir block, f16): byte(b,k) = (b>>4)*16384 + (k>>3)*256
//   + (b&15)*16 + (k&7)*2  -> one MFMA A-fragment = contiguous 16B/lane.
// 4 h phases; flag publish precedes FC (reuse distance 4 steps = safe).
// LDS: WhT [128][512] f16 xor-swizzled (131072 B) resident, GT [128][68] (17408 B).
#define SMEM_BYTES (131072 + 17408)

// one sub-chunk = 2 kc (4 loads, 16 MFMA)
#define ISSUE2(D, CC)                                                          \
  _Pragma("unroll") for (int mi = 0; mi < 2; ++mi)                             \
  _Pragma("unroll") for (int j = 0; j < 2; ++j)                                \
      D[mi][j] = load_frag(rs, hbuf, aoff[mi] + (unsigned)(((CC) * 2 + j) * 1024));

#define COMPUTE2(D, CC)                                                        \
  _Pragma("unroll") for (int j = 0; j < 2; ++j) {                              \
    const int kcabs = ks * 8 + (CC) * 2 + j;                                   \
    half8 bf[4];                                                               \
    _Pragma("unroll") for (int ni = 0; ni < 4; ++ni)                           \
        bf[ni] = *(const half8*)((const char*)smem + brow[ni] +                \
                                 (((kcabs * 4 + kq) ^ bxor[ni]) * 16));        \
    _Pragma("unroll") for (int mi = 0; mi < 2; ++mi)                           \
    _Pragma("unroll") for (int ni = 0; ni < 4; ++ni)                           \
        acc[mi][ni] = __builtin_amdgcn_mfma_f32_16x16x32_f16(                  \
            D[mi][j], bf[ni], acc[mi][ni], 0, 0, 0);                           \
  }

__global__ __launch_bounds__(512, 1) void bilstm_persist(
    const float* __restrict__ wxt, const int* __restrict__ xT,
    const _Float16* __restrict__ whr, const _Float16* __restrict__ wfc16,
    _Float16* __restrict__ hbuf, unsigned* __restrict__ flags,
    float* __restrict__ out) {
  extern __shared__ char smem[];
  _Float16* GT = (_Float16*)(smem + 131072);

  const int tid = threadIdx.x;
  const int lane = tid & 63;
  const int w = tid >> 6;         // 0..7
  const int ks = w >> 2;          // K-split half
  const int wl = w & 3;           // subtile within 64x128
  const int bid = blockIdx.x;
  const int grp = bid >> 4;       // 0..15
  const int nt = bid & 15;        // 0..15
  const int dir = grp >> 3;
  const int mt = grp & 7;
  const int b0 = mt * 64;

  // ---- prologue: Wh slice -> LDS, swizzled via pre-swizzled GLOBAL source ----
  {
    const char* wsrc = (const char*)(whr + ((size_t)(dir * 2048 + nt * 128)) * Hd);
#pragma unroll
    for (int i = 0; i < 16; ++i) {
      int e = i * 512 + tid;
      int n = e >> 6, cs = e & 63;
      load_lds16(wsrc + (size_t)n * 1024 + (size_t)(((cs ^ (n & 7)) * 16)),
                 (char*)smem + (size_t)e * 16);
    }
  }

  const int l15 = lane & 15;
  const int kq = lane >> 4;                 // 0..3
  const int wm0 = (wl & 1) * 32;            // m-half within 64
  const int wn0 = (wl >> 1) * 64;           // n-half within 128

#if USE_BUFLD
  const __amdgpu_buffer_rsrc_t rs = __builtin_amdgcn_make_buffer_rsrc(
      (void*)hbuf, (short)0, (int)(4u * 2u * 524288u), 0x00020000);
#else
  const __amdgpu_buffer_rsrc_t rs = 0;
#endif

  // A-fragment per-lane offsets (phase-independent; includes K-split offset)
  const unsigned bt_base = (unsigned)((b0 >> 4) + (wl & 1) * 2);
  unsigned aoff_lane[2];
#pragma unroll
  for (int mi = 0; mi < 2; ++mi)
    aoff_lane[mi] = (bt_base + mi) * 16384u + kq * 256u + l15 * 16u +
                    (unsigned)ks * 8192u;

  int brow[4], bxor[4];
#pragma unroll
  for (int ni = 0; ni < 4; ++ni) {
    int n = wn0 + ni * 16 + l15;
    brow[ni] = n * 1024;
    bxor[ni] = n & 7;
  }

  float creg[4];                             // c-state: 4 (b,k) pairs per thread
#pragma unroll
  for (int i = 0; i < 4; ++i) creg[i] = 0.f;

  const int bl = tid & 63;                   // epilogue: b within tile
  const int kh = tid >> 6;                   // epilogue: 4-k quad group (0..7)
  const int fcn = nt & 7;                    // FC v-tile
  // epilogue h-store offset (phase-independent): k = nt*32 + kh*4 .. +4
  const unsigned soff_lane = (unsigned)(((b0 + bl) >> 4)) * 16384u +
                             (unsigned)(nt * 4 + (kh >> 1)) * 256u +
                             (unsigned)(bl & 15) * 16u + (unsigned)(kh & 1) * 8u;
  // FC per-lane offset (phase-independent; K-split)
  const unsigned fcoff_lane = (unsigned)((b0 >> 4) + wl) * 16384u + kq * 256u +
                              l15 * 16u + (unsigned)ks * 8192u;

  __syncthreads();                           // WhT ready (drains global_load_lds)

  for (int s = 0; s <= Sd; ++s) {
    const unsigned ph = (unsigned)(s & 3);
    const unsigned abase = (ph * 2u + (unsigned)dir) * 524288u;          // read phase
    const unsigned nbase = (((unsigned)(s + 1) & 3u) * 2u + (unsigned)dir) * 524288u;

    if (s < Sd) {
      unsigned aoff[2];
      aoff[0] = abase + aoff_lane[0];
      aoff[1] = abase + aoff_lane[1];
      float4v acc[2][4];
#pragma unroll
      for (int mi = 0; mi < 2; ++mi)
#pragma unroll
        for (int ni = 0; ni < 4; ++ni) acc[mi][ni] = (float4v)0.f;

      half8 a0[2][2], a1[2][2], a2[2][2], a3[2][2];
      ISSUE2(a0, 0)
      ISSUE2(a1, 1)
      ISSUE2(a2, 2)
      COMPUTE2(a0, 0)
      ISSUE2(a3, 3)
      COMPUTE2(a1, 1)
      COMPUTE2(a2, 2)
      COMPUTE2(a3, 3)

      // epilogue operand prefetch (off the critical path: issue before GT syncs)
      const int t = dir ? (Sd - 1 - s) : s;
      const int b = b0 + bl;
      const int xv = xT[t * Bd + b];
      const float* wrow = wxt + ((size_t)(dir * Vd + xv)) * 2048 + nt * 128 + kh * 16;
      float4 wv[4];
#pragma unroll
      for (int kl = 0; kl < 4; ++kl) wv[kl] = *(const float4*)&wrow[kl * 4];

      // ---- K-split merge through GT ----
      if (ks == 1) {
        // high half writes f16 partials
#pragma unroll
        for (int mi = 0; mi < 2; ++mi) {
          int m = wm0 + mi * 16 + kq * 4;
#pragma unroll
          for (int ni = 0; ni < 4; ++ni) {
            int n = wn0 + ni * 16 + l15;
            half4v hv4;
            hv4[0] = (_Float16)acc[mi][ni][0];
            hv4[1] = (_Float16)acc[mi][ni][1];
            hv4[2] = (_Float16)acc[mi][ni][2];
            hv4[3] = (_Float16)acc[mi][ni][3];
            *(half4v*)&GT[n * 68 + m] = hv4;
          }
        }
      }
      __syncthreads();
      if (ks == 0) {
        // low half adds high partial (f32) and writes the final f16
#pragma unroll
        for (int mi = 0; mi < 2; ++mi) {
          int m = wm0 + mi * 16 + kq * 4;
#pragma unroll
          for (int ni = 0; ni < 4; ++ni) {
            int n = wn0 + ni * 16 + l15;
            half4v g4 = *(half4v*)&GT[n * 68 + m];
            half4v hv4;
            hv4[0] = (_Float16)(acc[mi][ni][0] + (float)g4[0]);
            hv4[1] = (_Float16)(acc[mi][ni][1] + (float)g4[1]);
            hv4[2] = (_Float16)(acc[mi][ni][2] + (float)g4[2]);
            hv4[3] = (_Float16)(acc[mi][ni][3] + (float)g4[3]);
            *(half4v*)&GT[n * 68 + m] = hv4;
          }
        }
      }
      __syncthreads();

      // pointwise: thread (bl, kh) owns b = b0+bl, kloc = kh*4 .. +4
      half4v hv;
#pragma unroll
      for (int kl = 0; kl < 4; ++kl) {
        int kloc = kh * 4 + kl;
        float g0 = (float)GT[(kloc * 4 + 0) * 68 + bl] + wv[kl].x;
        float g1 = (float)GT[(kloc * 4 + 1) * 68 + bl] + wv[kl].y;
        float g2 = (float)GT[(kloc * 4 + 2) * 68 + bl] + wv[kl].z;
        float g3 = (float)GT[(kloc * 4 + 3) * 68 + bl] + wv[kl].w;
        float gi = sigf(g0), gf = sigf(g1), go = sigf(g2), gg = tanhfast(g3);
        float cn = gf * creg[kl] + gi * gg;
        creg[kl] = cn;
        hv[kl] = (_Float16)(go * tanhfast(cn));
      }
      storeh4_coh(hbuf, nbase + soff_lane, hv);

      // Drain h-stores (syncthreads waits vmcnt(0) in each wave), then publish
      // EARLY so the group-barrier cost overlaps with the FC below.
      __syncthreads();
      if (tid == 0)
        __hip_atomic_store(&flags[bid * 32], (unsigned)(s + 1), __ATOMIC_RELAXED,
                           __HIP_MEMORY_SCOPE_AGENT);
    }

    // ---- FC of previous step's h: in-group, 8 blocks x (64b x 16v), K-split 2-way.
    // Reads phase ph (own group rows). Safe vs overwrite at step s+3: writers
    // need this block's flag >= s+3, published only after this FC completes.
    const bool fc_act = (s & 1) ? (nt < 8) : (nt >= 8);
    if (s > 0 && fc_act) {
      const unsigned fo = abase + fcoff_lane;
      const _Float16* Bfc = wfc16 + (size_t)dir * (Vd * Hd) +
                            (size_t)(fcn * 16 + l15) * Hd + kq * 8 + ks * 256;
      half8 aF[8];
#pragma unroll
      for (int k = 0; k < 8; ++k) aF[k] = load_frag(rs, hbuf, fo + k * 1024u);
      float4v fa = (float4v)0.f;
#pragma unroll
      for (int k = 0; k < 8; ++k)
        fa = __builtin_amdgcn_mfma_f32_16x16x32_f16(aF[k], *(const half8*)(Bfc + k * 32),
                                                    fa, 0, 0, 0);
      const int tf = dir ? (Sd - s) : (s - 1);
      const int v = fcn * 16 + l15;
      const int bb = b0 + wl * 16 + kq * 4;
      float* op = out + ((size_t)bb * Sd + tf) * Vd + v;
#pragma unroll
      for (int r2 = 0; r2 < 4; ++r2)
        unsafeAtomicAdd(op + (size_t)r2 * (Sd * Vd), fa[r2]);
    }

    if (s == Sd) break;

    // ---- group barrier: 16 blocks, poll own-group flags ----
    if (tid < 16) {
      unsigned* f = flags + (grp * 16 + tid) * 32;
      while (__hip_atomic_load(f, __ATOMIC_RELAXED, __HIP_MEMORY_SCOPE_AGENT) <
             (unsigned)(s + 1))
        __builtin_amdgcn_s_sleep(1);
    }
    __syncthreads();
  }
}

extern "C" void kernel_launch(void* const* d_in, const int* in_sizes, int n_in,
                              void* d_out, int out_size, void* d_ws, size_t ws_size,
                              hipStream_t stream) {
  (void)in_sizes; (void)n_in; (void)out_size; (void)ws_size;
  const int* x      = (const int*)d_in[0];
  const float* WxF  = (const float*)d_in[1];
  const float* WhF  = (const float*)d_in[2];
  const float* bxF  = (const float*)d_in[3];
  const float* bhF  = (const float*)d_in[4];
  const float* WxB  = (const float*)d_in[5];
  const float* WhB  = (const float*)d_in[6];
  const float* bxB  = (const float*)d_in[7];
  const float* bhB  = (const float*)d_in[8];
  const float* Wfc  = (const float*)d_in[9];
  const float* bfc  = (const float*)d_in[10];
  float* out = (float*)d_out;

  // ws (float units):
  //   wxt    @ 0        : 524288
  //   hbuf   @ 524288   : 1048576  (f16, 4 phases x 2 dir x 512 x 512)
  //   flags  @ 1572864  : 8192     (unsigned, 256 x 32)
  //   wh16   @ 1581056  : 1048576  (f16, 2 dir x 2048 x 512)
  //   wfc16  @ 2629632  : 65536    (f16, 2 dir x 128 x 512)
  //   xT     @ 2695168  : 131072   (int, 256 x 512)
  float* ws = (float*)d_ws;
  float* wxt        = ws;
  _Float16* hbuf    = (_Float16*)(ws + 524288);
  unsigned* flags   = (unsigned*)(ws + 1572864);
  _Float16* wh16    = (_Float16*)(ws + 1581056);
  _Float16* wfc16   = (_Float16*)(ws + 2629632);
  int* xT           = (int*)(ws + 2695168);

  prep_wxt<<<2048, 256, 0, stream>>>(WxF, bxF, bhF, WxB, bxB, bhB, wxt);
  prep_wh16<<<8192, 256, 0, stream>>>(WhF, WhB, wh16);
  prep_wfc16<<<512, 256, 0, stream>>>(Wfc, wfc16);
  prep_xT<<<512, 256, 0, stream>>>(x, xT);
  init_zero<<<256, 256, 0, stream>>>(ws + 524288);    // h phase 0 (1 MB)
  init_zero<<<8, 256, 0, stream>>>(ws + 1572864);     // flags
  init_out<<<16384, 256, 0, stream>>>(bfc, out);

  static bool attr_set = false;
  if (!attr_set) {
    (void)hipFuncSetAttribute((const void*)bilstm_persist,
                              hipFuncAttributeMaxDynamicSharedMemorySize, SMEM_BYTES);
    attr_set = true;
  }
  void* kargs[] = {(void*)&wxt, (void*)&xT, (void*)&wh16, (void*)&wfc16,
                   (void*)&hbuf, (void*)&flags, (void*)&out};
  if (hipLaunchCooperativeKernel((const void*)bilstm_persist, dim3(256), dim3(512),
                                 kargs, SMEM_BYTES, stream) != hipSuccess) {
    // fallback: plain launch — 148 KB LDS forces 1 block/CU, 256 blocks on 256 CUs
    bilstm_persist<<<dim3(256), dim3(512), SMEM_BYTES, stream>>>(
        wxt, xT, wh16, wfc16, hbuf, flags, out);
  }
}

// Round 7
// 1614.099 us; speedup vs baseline: 9.6024x; 1.0881x over previous
//
#include <hip/hip_runtime.h>

#define Hd 512
#define Bd 512
#define Vd 128
#define Sd 256

typedef _Float16 half8 __attribute__((ext_vector_type(8)));
typedef _Float16 half4v __attribute__((ext_vector_type(4)));
typedef float float4v __attribute__((ext_vector_type(4)));
typedef unsigned int uint4v __attribute__((ext_vector_type(4)));

__device__ __forceinline__ float sigf(float v) { return 1.0f / (1.0f + __expf(-v)); }
__device__ __forceinline__ float tanhfast(float v) { return 1.0f - 2.0f / (__expf(2.0f * v) + 1.0f); }

__device__ __forceinline__ void load_lds16(const void* g, void* l) {
  __builtin_amdgcn_global_load_lds(
      (const __attribute__((address_space(1))) unsigned int*)g,
      (__attribute__((address_space(3))) unsigned int*)l, 16, 0, 0);
}

#if __has_builtin(__builtin_amdgcn_raw_buffer_load_b128) && \
    __has_builtin(__builtin_amdgcn_make_buffer_rsrc)
#define USE_BUFLD 1
#else
#define USE_BUFLD 0
#endif

// Intra-XCD coherent 16B load: CPol=1 (sc0) bypasses L1, reads the XCD's L2.
// Producer blocks are pinned to the same XCD; their plain (write-through L1)
// stores land in that L2 -> single-L2-owner coherence, no L3 round trip.
#if USE_BUFLD
__device__ __forceinline__ half8 load_frag(__amdgpu_buffer_rsrc_t rs,
                                           const _Float16* base, unsigned voff) {
  uint4v d = __builtin_amdgcn_raw_buffer_load_b128(rs, voff, 0, 1 /*sc0*/);
  union { uint4v u; half8 h; } cv; cv.u = d;
  return cv.h;
}
#else
typedef int __amdgpu_buffer_rsrc_t;
__device__ __forceinline__ half8 load_frag(__amdgpu_buffer_rsrc_t rs,
                                           const _Float16* base, unsigned voff) {
  (void)rs;
  const char* p = (const char*)base + voff;
  union { unsigned long long u[2]; half8 h; } cv;
  cv.u[0] = __hip_atomic_load((const unsigned long long*)p, __ATOMIC_RELAXED,
                              __HIP_MEMORY_SCOPE_AGENT);
  cv.u[1] = __hip_atomic_load((const unsigned long long*)(p + 8), __ATOMIC_RELAXED,
                              __HIP_MEMORY_SCOPE_AGENT);
  return cv.h;
}
#endif

// Plain h store: write-through L1 -> dirty in own-XCD L2, tracked by vmcnt.
__device__ __forceinline__ void storeh4(_Float16* base, unsigned voff, half4v v) {
  *(half4v*)((char*)base + voff) = v;
}

// wxt[dir][v][n] = Wx[g][k][v] + bx[g*H+k] + bh[g*H+k], n = (k<<2)|g. fp32.
__global__ __launch_bounds__(256) void prep_wxt(
    const float* __restrict__ WxF, const float* __restrict__ bxF, const float* __restrict__ bhF,
    const float* __restrict__ WxB, const float* __restrict__ bxB, const float* __restrict__ bhB,
    float* __restrict__ wxt) {
  int e = blockIdx.x * 256 + threadIdx.x;   // 0..524287
  int n = e & 2047;
  int v = (e >> 11) & 127;
  int dir = e >> 18;
  int k = n >> 2, g = n & 3;
  const float* Wx = dir ? WxB : WxF;
  const float* bx = dir ? bxB : bxF;
  const float* bh = dir ? bhB : bhF;
  int gk = g * Hd + k;
  wxt[e] = Wx[gk * Vd + v] + bx[gk] + bh[gk];
}

// whr[dir][n][hc] f16 = Wh_dir[g][k][hc], n = (k<<2)|g
__global__ __launch_bounds__(256) void prep_wh16(
    const float* __restrict__ WhF, const float* __restrict__ WhB, _Float16* __restrict__ whr) {
  int e = blockIdx.x * 256 + threadIdx.x;   // 0..2097151
  int hc = e & 511;
  int n = (e >> 9) & 2047;
  int dir = e >> 20;
  int k = n >> 2, g = n & 3;
  const float* Wh = dir ? WhB : WhF;
  whr[e] = (_Float16)Wh[(g * Hd + k) * Hd + hc];
}

// wfc16[dir][v][hc] f16 = Wfc[v][dir*512+hc]
__global__ __launch_bounds__(256) void prep_wfc16(
    const float* __restrict__ Wfc, _Float16* __restrict__ wfc16) {
  int e = blockIdx.x * 256 + threadIdx.x;   // 0..131071
  int hc = e & 511;
  int v = (e >> 9) & 127;
  int dir = e >> 16;
  wfc16[e] = (_Float16)Wfc[v * 1024 + dir * 512 + hc];
}

// xT[t][b] = x[b][t]
__global__ __launch_bounds__(256) void prep_xT(const int* __restrict__ x, int* __restrict__ xT) {
  int e = blockIdx.x * 256 + threadIdx.x;   // 0..131071
  int t = e >> 9, b = e & 511;
  xT[e] = x[b * Sd + t];
}

__global__ __launch_bounds__(256) void init_zero(float* __restrict__ p) {
  int e = blockIdx.x * 256 + threadIdx.x;
  float4 z; z.x = 0.f; z.y = 0.f; z.z = 0.f; z.w = 0.f;
  ((float4*)p)[e] = z;
}

__global__ __launch_bounds__(256) void init_out(const float* __restrict__ bfc,
                                                float* __restrict__ out) {
  int e = blockIdx.x * 256 + threadIdx.x;
  int v0 = (e & 31) * 4;
  ((float4*)out)[e] = *(const float4*)&bfc[v0];
}

// ---------------------------------------------------------------------------
// Persistent BiLSTM. 256 blocks x 512 threads, XCD-pinned groups.
// Self-org: xcd = s_getreg(HW_REG_XCC_ID); rank = atomicAdd(xcdctr[xcd]);
//   grp = xcd*2 + (rank>>4) (16 blocks/group, ALL on one XCD); nt = rank&15.
//   dir = grp>>3; mt = grp&7. All h data traffic stays in the XCD's L2.
// Flags use agent-scope ATOMICS (un-hoistable, r5-proven); h data uses plain
//   stores + sc0 buffer loads (intra-XCD L2 coherent, ~200cy not ~700cy).
// Wave w: ks = w>>2 (K half), wl = w&3 (m-quarter: 16 rows x 128 n) -> no
//   duplicated A loads; FC reuses the K-loop A-fragments from registers.
// h layout (per phase-dir block, f16): byte(b,k) = (b>>4)*16384 + (k>>3)*256
//   + (b&15)*16 + (k&7)*2  -> one MFMA A-fragment = contiguous 16B/lane.
// 4 h phases; flag publish precedes FC (reuse distance 4 steps = safe).
// LDS: WhT [128][512] f16 xor-swizzled (131072 B) resident, GT [128][68] (17408 B).
#define SMEM_BYTES (131072 + 17408)

#define ISSUE2(D, C)                                                           \
  _Pragma("unroll") for (int j = 0; j < 2; ++j)                                \
      D[j] = load_frag(rs, hbuf, aoff + (unsigned)(((C) * 2 + j) * 1024));

#define COMPUTE2(D, C)                                                         \
  _Pragma("unroll") for (int j = 0; j < 2; ++j) {                              \
    const int kcabs = ks * 8 + (C) * 2 + j;                                    \
    _Pragma("unroll") for (int ni = 0; ni < 8; ++ni) {                         \
      half8 bf = *(const half8*)((const char*)smem + brow[ni] +                \
                                 (((kcabs * 4 + kq) ^ bxor[ni]) * 16));        \
      acc[ni] = __builtin_amdgcn_mfma_f32_16x16x32_f16(D[j], bf, acc[ni], 0, 0, 0); \
    }                                                                          \
  }

#define FCC(D, C)                                                              \
  _Pragma("unroll") for (int j = 0; j < 2; ++j)                                \
      fa = __builtin_amdgcn_mfma_f32_16x16x32_f16(                             \
          D[j], *(const half8*)(Bfc + ((C) * 2 + j) * 32), fa, 0, 0, 0);

__global__ __launch_bounds__(512, 1) void bilstm_persist(
    const float* __restrict__ wxt, const int* __restrict__ xT,
    const _Float16* __restrict__ whr, const _Float16* __restrict__ wfc16,
    _Float16* __restrict__ hbuf, unsigned* __restrict__ flags,
    float* __restrict__ out) {
  extern __shared__ char smem[];
  _Float16* GT = (_Float16*)(smem + 131072);

  const int tid = threadIdx.x;
  const int lane = tid & 63;
  const int w = tid >> 6;         // 0..7
  const int ks = w >> 2;          // K-split half
  const int wl = w & 3;           // m-quarter (16 rows)

  // ---- self-organize: role from (physical XCD, rank-within-XCD) ----
  unsigned xcd;
  asm volatile("s_getreg_b32 %0, hwreg(HW_REG_XCC_ID)" : "=s"(xcd));
  xcd &= 7u;
  unsigned* xcdctr = flags + 8176;
  int* roleSh = (int*)GT;
  if (tid == 0) roleSh[0] = (int)atomicAdd(&xcdctr[xcd], 1u);
  __syncthreads();
  const int rank = roleSh[0];                // 0..31 (32 CUs/XCD, 1 block/CU)
  const int grp = (int)xcd * 2 + (rank >> 4);
  const int nt = rank & 15;
  const int dir = grp >> 3;
  const int mt = grp & 7;
  const int b0 = mt * 64;
  __syncthreads();                           // roleSh read done (GT reused later)

  // ---- prologue: Wh slice -> LDS, swizzled via pre-swizzled GLOBAL source ----
  {
    const char* wsrc = (const char*)(whr + ((size_t)(dir * 2048 + nt * 128)) * Hd);
#pragma unroll
    for (int i = 0; i < 16; ++i) {
      int e = i * 512 + tid;
      int n = e >> 6, cs = e & 63;
      load_lds16(wsrc + (size_t)n * 1024 + (size_t)(((cs ^ (n & 7)) * 16)),
                 (char*)smem + (size_t)e * 16);
    }
  }

  const int l15 = lane & 15;
  const int kq = lane >> 4;                 // 0..3

#if USE_BUFLD
  const __amdgpu_buffer_rsrc_t rs = __builtin_amdgcn_make_buffer_rsrc(
      (void*)hbuf, (short)0, (int)4194304, 0x00020000);
#else
  const __amdgpu_buffer_rsrc_t rs = 0;
#endif

  // A-fragment per-lane offset (phase-independent; wave owns 16 distinct rows)
  const unsigned aoff_lane = (unsigned)((b0 >> 4) + wl) * 16384u + kq * 256u +
                             l15 * 16u + (unsigned)ks * 8192u;

  int brow[8], bxor[8];
#pragma unroll
  for (int ni = 0; ni < 8; ++ni) {
    int n = ni * 16 + l15;
    brow[ni] = n * 1024;
    bxor[ni] = n & 7;
  }

  float creg[4];                             // c-state: 4 (b,k) pairs per thread
#pragma unroll
  for (int i = 0; i < 4; ++i) creg[i] = 0.f;

  const int bl = tid & 63;                   // epilogue: b within tile
  const int kh = tid >> 6;                   // epilogue: 4-k quad group (0..7)
  const int fcn = nt & 7;                    // FC v-tile
  const int gtm = wl * 16 + kq * 4;          // GT row base for this wave's lanes
  // epilogue h-store offset (phase-independent): k = nt*32 + kh*4 .. +4
  const unsigned soff_lane = (unsigned)(((b0 + bl) >> 4)) * 16384u +
                             (unsigned)(nt * 4 + (kh >> 1)) * 256u +
                             (unsigned)(bl & 15) * 16u + (unsigned)(kh & 1) * 8u;

  __syncthreads();                           // WhT ready (drains global_load_lds)

  for (int s = 0; s <= Sd; ++s) {
    const unsigned abase = (((unsigned)(s & 3)) * 2u + (unsigned)dir) * 524288u;
    const unsigned nbase = (((unsigned)(s + 1) & 3u) * 2u + (unsigned)dir) * 524288u;
    const unsigned aoff = abase + aoff_lane;

    half8 a0[2], a1[2], a2[2], a3[2];        // live through FC (register reuse)

    if (s < Sd) {
      float4v acc[8];
#pragma unroll
      for (int ni = 0; ni < 8; ++ni) acc[ni] = (float4v)0.f;

      ISSUE2(a0, 0)
      ISSUE2(a1, 1)
      ISSUE2(a2, 2)
      COMPUTE2(a0, 0)
      ISSUE2(a3, 3)
      COMPUTE2(a1, 1)
      COMPUTE2(a2, 2)
      COMPUTE2(a3, 3)

      // epilogue operand prefetch (hidden under the GT barriers)
      const int t = dir ? (Sd - 1 - s) : s;
      const int b = b0 + bl;
      const int xv = xT[t * Bd + b];
      const float* wrow = wxt + ((size_t)(dir * Vd + xv)) * 2048 + nt * 128 + kh * 16;
      float4 wv[4];
#pragma unroll
      for (int kl = 0; kl < 4; ++kl) wv[kl] = *(const float4*)&wrow[kl * 4];

      // ---- K-split merge through GT ----
      if (ks == 1) {
#pragma unroll
        for (int ni = 0; ni < 8; ++ni) {
          int n = ni * 16 + l15;
          half4v hv4;
          hv4[0] = (_Float16)acc[ni][0];
          hv4[1] = (_Float16)acc[ni][1];
          hv4[2] = (_Float16)acc[ni][2];
          hv4[3] = (_Float16)acc[ni][3];
          *(half4v*)&GT[n * 68 + gtm] = hv4;
        }
      }
      __syncthreads();
      if (ks == 0) {
#pragma unroll
        for (int ni = 0; ni < 8; ++ni) {
          int n = ni * 16 + l15;
          half4v g4 = *(half4v*)&GT[n * 68 + gtm];
          half4v hv4;
          hv4[0] = (_Float16)(acc[ni][0] + (float)g4[0]);
          hv4[1] = (_Float16)(acc[ni][1] + (float)g4[1]);
          hv4[2] = (_Float16)(acc[ni][2] + (float)g4[2]);
          hv4[3] = (_Float16)(acc[ni][3] + (float)g4[3]);
          *(half4v*)&GT[n * 68 + gtm] = hv4;
        }
      }
      __syncthreads();

      // pointwise: thread (bl, kh) owns b = b0+bl, kloc = kh*4 .. +4
      half4v hv;
#pragma unroll
      for (int kl = 0; kl < 4; ++kl) {
        int kloc = kh * 4 + kl;
        float g0 = (float)GT[(kloc * 4 + 0) * 68 + bl] + wv[kl].x;
        float g1 = (float)GT[(kloc * 4 + 1) * 68 + bl] + wv[kl].y;
        float g2 = (float)GT[(kloc * 4 + 2) * 68 + bl] + wv[kl].z;
        float g3 = (float)GT[(kloc * 4 + 3) * 68 + bl] + wv[kl].w;
        float gi = sigf(g0), gf = sigf(g1), go = sigf(g2), gg = tanhfast(g3);
        float cn = gf * creg[kl] + gi * gg;
        creg[kl] = cn;
        hv[kl] = (_Float16)(go * tanhfast(cn));
      }
      storeh4(hbuf, nbase + soff_lane, hv);

      // Drain h-stores (syncthreads waits vmcnt(0) in each wave), then publish
      // EARLY with an agent atomic (un-hoistable, r5-proven path); barrier cost
      // overlaps with the FC below.
      __syncthreads();
      if (tid == 0)
        __hip_atomic_store(&flags[(grp * 16 + nt) * 32], (unsigned)(s + 1),
                           __ATOMIC_RELAXED, __HIP_MEMORY_SCOPE_AGENT);
    } else {
      // last iteration: K-loop skipped, but FC still needs the A-fragments.
      ISSUE2(a0, 0)
      ISSUE2(a1, 1)
      ISSUE2(a2, 2)
      ISSUE2(a3, 3)
    }

    // ---- FC of previous step's h: register-reuse of A-fragments, zero h loads.
    const bool fc_act = (s & 1) ? (nt < 8) : (nt >= 8);
    if (s > 0 && fc_act) {
      const _Float16* Bfc = wfc16 + (size_t)dir * (Vd * Hd) +
                            (size_t)(fcn * 16 + l15) * Hd + ks * 256 + kq * 8;
      float4v fa = (float4v)0.f;
      FCC(a0, 0)
      FCC(a1, 1)
      FCC(a2, 2)
      FCC(a3, 3)
      const int tf = dir ? (Sd - s) : (s - 1);
      const int v = fcn * 16 + l15;
      const int bb = b0 + wl * 16 + kq * 4;
      float* op = out + ((size_t)bb * Sd + tf) * Vd + v;
#pragma unroll
      for (int r2 = 0; r2 < 4; ++r2)
        unsafeAtomicAdd(op + (size_t)r2 * (Sd * Vd), fa[r2]);
    }

    if (s == Sd) break;

    // ---- group barrier: 16 blocks, atomic polls (cannot be hoisted) ----
    if (tid < 16) {
      unsigned* f = flags + (grp * 16 + tid) * 32;
      while (__hip_atomic_load(f, __ATOMIC_RELAXED, __HIP_MEMORY_SCOPE_AGENT) <
             (unsigned)(s + 1))
        __builtin_amdgcn_s_sleep(1);
    }
    __syncthreads();
  }
}

extern "C" void kernel_launch(void* const* d_in, const int* in_sizes, int n_in,
                              void* d_out, int out_size, void* d_ws, size_t ws_size,
                              hipStream_t stream) {
  (void)in_sizes; (void)n_in; (void)out_size; (void)ws_size;
  const int* x      = (const int*)d_in[0];
  const float* WxF  = (const float*)d_in[1];
  const float* WhF  = (const float*)d_in[2];
  const float* bxF  = (const float*)d_in[3];
  const float* bhF  = (const float*)d_in[4];
  const float* WxB  = (const float*)d_in[5];
  const float* WhB  = (const float*)d_in[6];
  const float* bxB  = (const float*)d_in[7];
  const float* bhB  = (const float*)d_in[8];
  const float* Wfc  = (const float*)d_in[9];
  const float* bfc  = (const float*)d_in[10];
  float* out = (float*)d_out;

  // ws (float units):
  //   wxt    @ 0        : 524288
  //   hbuf   @ 524288   : 1048576  (f16, 4 phases x 2 dir x 512 x 512)
  //   flags  @ 1572864  : 8192     (unsigned; [0..8159] flags, [8176..8183] xcdctr)
  //   wh16   @ 1581056  : 1048576  (f16, 2 dir x 2048 x 512)
  //   wfc16  @ 2629632  : 65536    (f16, 2 dir x 128 x 512)
  //   xT     @ 2695168  : 131072   (int, 256 x 512)
  float* ws = (float*)d_ws;
  float* wxt        = ws;
  _Float16* hbuf    = (_Float16*)(ws + 524288);
  unsigned* flags   = (unsigned*)(ws + 1572864);
  _Float16* wh16    = (_Float16*)(ws + 1581056);
  _Float16* wfc16   = (_Float16*)(ws + 2629632);
  int* xT           = (int*)(ws + 2695168);

  prep_wxt<<<2048, 256, 0, stream>>>(WxF, bxF, bhF, WxB, bxB, bhB, wxt);
  prep_wh16<<<8192, 256, 0, stream>>>(WhF, WhB, wh16);
  prep_wfc16<<<512, 256, 0, stream>>>(Wfc, wfc16);
  prep_xT<<<512, 256, 0, stream>>>(x, xT);
  init_zero<<<256, 256, 0, stream>>>(ws + 524288);    // h phase 0 (1 MB)
  init_zero<<<8, 256, 0, stream>>>(ws + 1572864);     // flags + xcdctr
  init_out<<<16384, 256, 0, stream>>>(bfc, out);

  static bool attr_set = false;
  if (!attr_set) {
    (void)hipFuncSetAttribute((const void*)bilstm_persist,
                              hipFuncAttributeMaxDynamicSharedMemorySize, SMEM_BYTES);
    attr_set = true;
  }
  void* kargs[] = {(void*)&wxt, (void*)&xT, (void*)&wh16, (void*)&wfc16,
                   (void*)&hbuf, (void*)&flags, (void*)&out};
  if (hipLaunchCooperativeKernel((const void*)bilstm_persist, dim3(256), dim3(512),
                                 kargs, SMEM_BYTES, stream) != hipSuccess) {
    // fallback: plain launch — 148 KB LDS forces 1 block/CU, 256 blocks on 256 CUs
    bilstm_persist<<<dim3(256), dim3(512), SMEM_BYTES, stream>>>(
        wxt, xT, wh16, wfc16, hbuf, flags, out);
  }
}

// Round 9
// 1463.349 us; speedup vs baseline: 10.5916x; 1.1030x over previous
//
#include <hip/hip_runtime.h>

#define Hd 512
#define Bd 512
#define Vd 128
#define Sd 256

typedef _Float16 half8 __attribute__((ext_vector_type(8)));
typedef _Float16 half4v __attribute__((ext_vector_type(4)));
typedef float float4v __attribute__((ext_vector_type(4)));
typedef unsigned int uint4v __attribute__((ext_vector_type(4)));

__device__ __forceinline__ float sigf(float v) { return 1.0f / (1.0f + __expf(-v)); }
__device__ __forceinline__ float tanhfast(float v) { return 1.0f - 2.0f / (__expf(2.0f * v) + 1.0f); }

__device__ __forceinline__ void load_lds16(const void* g, void* l) {
  __builtin_amdgcn_global_load_lds(
      (const __attribute__((address_space(1))) unsigned int*)g,
      (__attribute__((address_space(3))) unsigned int*)l, 16, 0, 0);
}

#if __has_builtin(__builtin_amdgcn_raw_buffer_load_b128) && \
    __has_builtin(__builtin_amdgcn_make_buffer_rsrc)
#define USE_BUFLD 1
#else
#define USE_BUFLD 0
#endif

// Intra-XCD coherent 16B load: CPol=1 (sc0) bypasses L1, reads the XCD's L2.
#if USE_BUFLD
__device__ __forceinline__ half8 load_frag(__amdgpu_buffer_rsrc_t rs,
                                           const _Float16* base, unsigned voff) {
  uint4v d = __builtin_amdgcn_raw_buffer_load_b128(rs, voff, 0, 1 /*sc0*/);
  union { uint4v u; half8 h; } cv; cv.u = d;
  return cv.h;
}
#else
typedef int __amdgpu_buffer_rsrc_t;
__device__ __forceinline__ half8 load_frag(__amdgpu_buffer_rsrc_t rs,
                                           const _Float16* base, unsigned voff) {
  (void)rs;
  const char* p = (const char*)base + voff;
  union { unsigned long long u[2]; half8 h; } cv;
  cv.u[0] = __hip_atomic_load((const unsigned long long*)p, __ATOMIC_RELAXED,
                              __HIP_MEMORY_SCOPE_AGENT);
  cv.u[1] = __hip_atomic_load((const unsigned long long*)(p + 8), __ATOMIC_RELAXED,
                              __HIP_MEMORY_SCOPE_AGENT);
  return cv.h;
}
#endif

// Plain h store: write-through L1 -> dirty in own-XCD L2, tracked by vmcnt.
__device__ __forceinline__ void storeh4(_Float16* base, unsigned voff, half4v v) {
  *(half4v*)((char*)base + voff) = v;
}

// wxt[dir][v][n] = Wx[g][k][v] + bx[g*H+k] + bh[g*H+k], n = (k<<2)|g. fp32.
__global__ __launch_bounds__(256) void prep_wxt(
    const float* __restrict__ WxF, const float* __restrict__ bxF, const float* __restrict__ bhF,
    const float* __restrict__ WxB, const float* __restrict__ bxB, const float* __restrict__ bhB,
    float* __restrict__ wxt) {
  int e = blockIdx.x * 256 + threadIdx.x;   // 0..524287
  int n = e & 2047;
  int v = (e >> 11) & 127;
  int dir = e >> 18;
  int k = n >> 2, g = n & 3;
  const float* Wx = dir ? WxB : WxF;
  const float* bx = dir ? bxB : bxF;
  const float* bh = dir ? bhB : bhF;
  int gk = g * Hd + k;
  wxt[e] = Wx[gk * Vd + v] + bx[gk] + bh[gk];
}

// whr[dir][n][hc] f16 = Wh_dir[g][k][hc], n = (k<<2)|g
__global__ __launch_bounds__(256) void prep_wh16(
    const float* __restrict__ WhF, const float* __restrict__ WhB, _Float16* __restrict__ whr) {
  int e = blockIdx.x * 256 + threadIdx.x;   // 0..2097151
  int hc = e & 511;
  int n = (e >> 9) & 2047;
  int dir = e >> 20;
  int k = n >> 2, g = n & 3;
  const float* Wh = dir ? WhB : WhF;
  whr[e] = (_Float16)Wh[(g * Hd + k) * Hd + hc];
}

// wfc16[dir][v][hc] f16 = Wfc[v][dir*512+hc]
__global__ __launch_bounds__(256) void prep_wfc16(
    const float* __restrict__ Wfc, _Float16* __restrict__ wfc16) {
  int e = blockIdx.x * 256 + threadIdx.x;   // 0..131071
  int hc = e & 511;
  int v = (e >> 9) & 127;
  int dir = e >> 16;
  wfc16[e] = (_Float16)Wfc[v * 1024 + dir * 512 + hc];
}

// xT[t][b] = x[b][t]
__global__ __launch_bounds__(256) void prep_xT(const int* __restrict__ x, int* __restrict__ xT) {
  int e = blockIdx.x * 256 + threadIdx.x;   // 0..131071
  int t = e >> 9, b = e & 511;
  xT[e] = x[b * Sd + t];
}

__global__ __launch_bounds__(256) void init_zero(float* __restrict__ p) {
  int e = blockIdx.x * 256 + threadIdx.x;
  float4 z; z.x = 0.f; z.y = 0.f; z.z = 0.f; z.w = 0.f;
  ((float4*)p)[e] = z;
}

__global__ __launch_bounds__(256) void init_out(const float* __restrict__ bfc,
                                                float* __restrict__ out) {
  int e = blockIdx.x * 256 + threadIdx.x;
  int v0 = (e & 31) * 4;
  ((float4*)out)[e] = *(const float4*)&bfc[v0];
}

// ---------------------------------------------------------------------------
// Persistent BiLSTM. 256 blocks x 512 threads, XCD-pinned groups.
// Self-org: xcd = s_getreg(HW_REG_XCC_ID); rank = atomicAdd(xcdctr[xcd]);
//   grp = xcd*2 + (rank>>4); nt = rank&15; dir = grp>>3; mt = grp&7.
// Wave w: ks = w>>2 (K half), wl = w&3 (m-quarter). B-frag register cache:
//   each wave holds kc-local 0..3 x 8 ni in VGPRs (32 frags = 128 VGPR),
//   filled once -> per-step LDS B-reads halve (512 -> 256 per CU).
// Flags: r7-proven agent-scope atomics (un-hoistable; NO asm — r8's asm poll
//   lacked early-clobber and clobbered its own address pair -> hang).
// h layout (per phase-dir block, f16): byte(b,k) = (b>>4)*16384 + (k>>3)*256
//   + (b&15)*16 + (k&7)*2. 4 h phases; flag publish precedes FC.
// LDS: WhT [128][512] f16 xor-swizzled (131072 B) resident, GT [128][68] (17408 B).
#define SMEM_BYTES (131072 + 17408)

#define ISSUE2(D, C)                                                           \
  _Pragma("unroll") for (int j = 0; j < 2; ++j)                                \
      D[j] = load_frag(rs, hbuf, aoff + (unsigned)(((C) * 2 + j) * 1024));

// cached-B compute: kc-local (C)*2+j in [0,4) -> registers, no LDS
#define COMPUTE2C(D, C)                                                        \
  _Pragma("unroll") for (int j = 0; j < 2; ++j) {                              \
    _Pragma("unroll") for (int ni = 0; ni < 8; ++ni)                           \
      acc[ni] = __builtin_amdgcn_mfma_f32_16x16x32_f16(                        \
          D[j], bcache[(C) * 2 + j][ni], acc[ni], 0, 0, 0);                    \
  }

// LDS-B compute: kc-local (C)*2+j in [4,8)
#define COMPUTE2L(D, C)                                                        \
  _Pragma("unroll") for (int j = 0; j < 2; ++j) {                              \
    const int kcabs = ks * 8 + (C) * 2 + j;                                    \
    _Pragma("unroll") for (int ni = 0; ni < 8; ++ni) {                         \
      half8 bf = *(const half8*)((const char*)smem + brow[ni] +                \
                                 (((kcabs * 4 + kq) ^ bxor[ni]) * 16));        \
      acc[ni] = __builtin_amdgcn_mfma_f32_16x16x32_f16(D[j], bf, acc[ni], 0, 0, 0); \
    }                                                                          \
  }

#define FCC(D, C)                                                              \
  _Pragma("unroll") for (int j = 0; j < 2; ++j)                                \
      fa = __builtin_amdgcn_mfma_f32_16x16x32_f16(                             \
          D[j], *(const half8*)(Bfc + ((C) * 2 + j) * 32), fa, 0, 0, 0);

__global__ __launch_bounds__(512, 1) void bilstm_persist(
    const float* __restrict__ wxt, const int* __restrict__ xT,
    const _Float16* __restrict__ whr, const _Float16* __restrict__ wfc16,
    _Float16* __restrict__ hbuf, unsigned* __restrict__ flags,
    float* __restrict__ out) {
  extern __shared__ char smem[];
  _Float16* GT = (_Float16*)(smem + 131072);

  const int tid = threadIdx.x;
  const int lane = tid & 63;
  const int w = tid >> 6;         // 0..7
  const int ks = w >> 2;          // K-split half
  const int wl = w & 3;           // m-quarter (16 rows)

  // ---- self-organize: role from (physical XCD, rank-within-XCD) ----
  unsigned xcd;
  asm volatile("s_getreg_b32 %0, hwreg(HW_REG_XCC_ID)" : "=s"(xcd));
  xcd &= 7u;
  unsigned* xcdctr = flags + 8176;
  int* roleSh = (int*)GT;
  if (tid == 0) roleSh[0] = (int)atomicAdd(&xcdctr[xcd], 1u);
  __syncthreads();
  const int rank = roleSh[0];                // 0..31 (32 CUs/XCD, 1 block/CU)
  const int grp = (int)xcd * 2 + (rank >> 4);
  const int nt = rank & 15;
  const int dir = grp >> 3;
  const int mt = grp & 7;
  const int b0 = mt * 64;
  __syncthreads();                           // roleSh read done (GT reused later)

  // ---- prologue: Wh slice -> LDS, swizzled via pre-swizzled GLOBAL source ----
  {
    const char* wsrc = (const char*)(whr + ((size_t)(dir * 2048 + nt * 128)) * Hd);
#pragma unroll
    for (int i = 0; i < 16; ++i) {
      int e = i * 512 + tid;
      int n = e >> 6, cs = e & 63;
      load_lds16(wsrc + (size_t)n * 1024 + (size_t)(((cs ^ (n & 7)) * 16)),
                 (char*)smem + (size_t)e * 16);
    }
  }

  const int l15 = lane & 15;
  const int kq = lane >> 4;                 // 0..3

#if USE_BUFLD
  const __amdgpu_buffer_rsrc_t rs = __builtin_amdgcn_make_buffer_rsrc(
      (void*)hbuf, (short)0, (int)4194304, 0x00020000);
#else
  const __amdgpu_buffer_rsrc_t rs = 0;
#endif

  // A-fragment per-lane offset (phase-independent; wave owns 16 distinct rows)
  const unsigned aoff_lane = (unsigned)((b0 >> 4) + wl) * 16384u + kq * 256u +
                             l15 * 16u + (unsigned)ks * 8192u;

  int brow[8], bxor[8];
#pragma unroll
  for (int ni = 0; ni < 8; ++ni) {
    int n = ni * 16 + l15;
    brow[ni] = n * 1024;
    bxor[ni] = n & 7;
  }

  float creg[4];                             // c-state: 4 (b,k) pairs per thread
#pragma unroll
  for (int i = 0; i < 4; ++i) creg[i] = 0.f;

  const int bl = tid & 63;                   // epilogue: b within tile
  const int kh = tid >> 6;                   // epilogue: 4-k quad group (0..7)
  const int fcn = nt & 7;                    // FC v-tile
  const int gtm = wl * 16 + kq * 4;          // GT row base for this wave's lanes
  // epilogue h-store offset (phase-independent): k = nt*32 + kh*4 .. +4
  const unsigned soff_lane = (unsigned)(((b0 + bl) >> 4)) * 16384u +
                             (unsigned)(nt * 4 + (kh >> 1)) * 256u +
                             (unsigned)(bl & 15) * 16u + (unsigned)(kh & 1) * 8u;

  __syncthreads();                           // WhT ready (drains global_load_lds)

  // ---- B-fragment register cache: kc-local 0..3 x 8 ni (one-time LDS read) ----
  half8 bcache[4][8];
#pragma unroll
  for (int c = 0; c < 4; ++c) {
    const int kcabs = ks * 8 + c;
#pragma unroll
    for (int ni = 0; ni < 8; ++ni)
      bcache[c][ni] = *(const half8*)((const char*)smem + brow[ni] +
                                      (((kcabs * 4 + kq) ^ bxor[ni]) * 16));
  }

  for (int s = 0; s <= Sd; ++s) {
    const unsigned abase = (((unsigned)(s & 3)) * 2u + (unsigned)dir) * 524288u;
    const unsigned nbase = (((unsigned)(s + 1) & 3u) * 2u + (unsigned)dir) * 524288u;
    const unsigned aoff = abase + aoff_lane;

    half8 a0[2], a1[2], a2[2], a3[2];        // live through FC (register reuse)

    if (s < Sd) {
      float4v acc[8];
#pragma unroll
      for (int ni = 0; ni < 8; ++ni) acc[ni] = (float4v)0.f;

      ISSUE2(a0, 0)
      ISSUE2(a1, 1)
      ISSUE2(a2, 2)
      COMPUTE2C(a0, 0)                       // cached B: runs while a2/a3 in flight
      ISSUE2(a3, 3)
      COMPUTE2C(a1, 1)
      COMPUTE2L(a2, 2)
      COMPUTE2L(a3, 3)

      // epilogue operand prefetch (hidden under the GT barriers)
      const int t = dir ? (Sd - 1 - s) : s;
      const int b = b0 + bl;
      const int xv = xT[t * Bd + b];
      const float* wrow = wxt + ((size_t)(dir * Vd + xv)) * 2048 + nt * 128 + kh * 16;
      float4 wv[4];
#pragma unroll
      for (int kl = 0; kl < 4; ++kl) wv[kl] = *(const float4*)&wrow[kl * 4];

      // ---- K-split merge through GT ----
      if (ks == 1) {
#pragma unroll
        for (int ni = 0; ni < 8; ++ni) {
          int n = ni * 16 + l15;
          half4v hv4;
          hv4[0] = (_Float16)acc[ni][0];
          hv4[1] = (_Float16)acc[ni][1];
          hv4[2] = (_Float16)acc[ni][2];
          hv4[3] = (_Float16)acc[ni][3];
          *(half4v*)&GT[n * 68 + gtm] = hv4;
        }
      }
      __syncthreads();
      if (ks == 0) {
#pragma unroll
        for (int ni = 0; ni < 8; ++ni) {
          int n = ni * 16 + l15;
          half4v g4 = *(half4v*)&GT[n * 68 + gtm];
          half4v hv4;
          hv4[0] = (_Float16)(acc[ni][0] + (float)g4[0]);
          hv4[1] = (_Float16)(acc[ni][1] + (float)g4[1]);
          hv4[2] = (_Float16)(acc[ni][2] + (float)g4[2]);
          hv4[3] = (_Float16)(acc[ni][3] + (float)g4[3]);
          *(half4v*)&GT[n * 68 + gtm] = hv4;
        }
      }
      __syncthreads();

      // pointwise: thread (bl, kh) owns b = b0+bl, kloc = kh*4 .. +4
      half4v hv;
#pragma unroll
      for (int kl = 0; kl < 4; ++kl) {
        int kloc = kh * 4 + kl;
        float g0 = (float)GT[(kloc * 4 + 0) * 68 + bl] + wv[kl].x;
        float g1 = (float)GT[(kloc * 4 + 1) * 68 + bl] + wv[kl].y;
        float g2 = (float)GT[(kloc * 4 + 2) * 68 + bl] + wv[kl].z;
        float g3 = (float)GT[(kloc * 4 + 3) * 68 + bl] + wv[kl].w;
        float gi = sigf(g0), gf = sigf(g1), go = sigf(g2), gg = tanhfast(g3);
        float cn = gf * creg[kl] + gi * gg;
        creg[kl] = cn;
        hv[kl] = (_Float16)(go * tanhfast(cn));
      }
      storeh4(hbuf, nbase + soff_lane, hv);

      // Drain h-stores (syncthreads waits vmcnt(0) in each wave), then publish
      // EARLY with an agent atomic (un-hoistable, r7-proven); barrier cost
      // overlaps with the FC below.
      __syncthreads();
      if (tid == 0)
        __hip_atomic_store(&flags[(grp * 16 + nt) * 32], (unsigned)(s + 1),
                           __ATOMIC_RELAXED, __HIP_MEMORY_SCOPE_AGENT);
    } else {
      // last iteration: K-loop skipped, but FC still needs the A-fragments.
      ISSUE2(a0, 0)
      ISSUE2(a1, 1)
      ISSUE2(a2, 2)
      ISSUE2(a3, 3)
    }

    // ---- FC of previous step's h: register-reuse of A-fragments, zero h loads.
    const bool fc_act = (s & 1) ? (nt < 8) : (nt >= 8);
    if (s > 0 && fc_act) {
      const _Float16* Bfc = wfc16 + (size_t)dir * (Vd * Hd) +
                            (size_t)(fcn * 16 + l15) * Hd + ks * 256 + kq * 8;
      float4v fa = (float4v)0.f;
      FCC(a0, 0)
      FCC(a1, 1)
      FCC(a2, 2)
      FCC(a3, 3)
      const int tf = dir ? (Sd - s) : (s - 1);
      const int v = fcn * 16 + l15;
      const int bb = b0 + wl * 16 + kq * 4;
      float* op = out + ((size_t)bb * Sd + tf) * Vd + v;
#pragma unroll
      for (int r2 = 0; r2 < 4; ++r2)
        unsafeAtomicAdd(op + (size_t)r2 * (Sd * Vd), fa[r2]);
    }

    if (s == Sd) break;

    // ---- group barrier: 16 blocks, atomic polls (cannot be hoisted) ----
    if (tid < 16) {
      unsigned* f = flags + (grp * 16 + tid) * 32;
      while (__hip_atomic_load(f, __ATOMIC_RELAXED, __HIP_MEMORY_SCOPE_AGENT) <
             (unsigned)(s + 1))
        __builtin_amdgcn_s_sleep(1);
    }
    __syncthreads();
  }
}

extern "C" void kernel_launch(void* const* d_in, const int* in_sizes, int n_in,
                              void* d_out, int out_size, void* d_ws, size_t ws_size,
                              hipStream_t stream) {
  (void)in_sizes; (void)n_in; (void)out_size; (void)ws_size;
  const int* x      = (const int*)d_in[0];
  const float* WxF  = (const float*)d_in[1];
  const float* WhF  = (const float*)d_in[2];
  const float* bxF  = (const float*)d_in[3];
  const float* bhF  = (const float*)d_in[4];
  const float* WxB  = (const float*)d_in[5];
  const float* WhB  = (const float*)d_in[6];
  const float* bxB  = (const float*)d_in[7];
  const float* bhB  = (const float*)d_in[8];
  const float* Wfc  = (const float*)d_in[9];
  const float* bfc  = (const float*)d_in[10];
  float* out = (float*)d_out;

  // ws (float units):
  //   wxt    @ 0        : 524288
  //   hbuf   @ 524288   : 1048576  (f16, 4 phases x 2 dir x 512 x 512)
  //   flags  @ 1572864  : 8192     (unsigned; [0..8159] flags, [8176..8183] xcdctr)
  //   wh16   @ 1581056  : 1048576  (f16, 2 dir x 2048 x 512)
  //   wfc16  @ 2629632  : 65536    (f16, 2 dir x 128 x 512)
  //   xT     @ 2695168  : 131072   (int, 256 x 512)
  float* ws = (float*)d_ws;
  float* wxt        = ws;
  _Float16* hbuf    = (_Float16*)(ws + 524288);
  unsigned* flags   = (unsigned*)(ws + 1572864);
  _Float16* wh16    = (_Float16*)(ws + 1581056);
  _Float16* wfc16   = (_Float16*)(ws + 2629632);
  int* xT           = (int*)(ws + 2695168);

  prep_wxt<<<2048, 256, 0, stream>>>(WxF, bxF, bhF, WxB, bxB, bhB, wxt);
  prep_wh16<<<8192, 256, 0, stream>>>(WhF, WhB, wh16);
  prep_wfc16<<<512, 256, 0, stream>>>(Wfc, wfc16);
  prep_xT<<<512, 256, 0, stream>>>(x, xT);
  init_zero<<<256, 256, 0, stream>>>(ws + 524288);    // h phase 0 (1 MB)
  init_zero<<<8, 256, 0, stream>>>(ws + 1572864);     // flags + xcdctr
  init_out<<<16384, 256, 0, stream>>>(bfc, out);

  static bool attr_set = false;
  if (!attr_set) {
    (void)hipFuncSetAttribute((const void*)bilstm_persist,
                              hipFuncAttributeMaxDynamicSharedMemorySize, SMEM_BYTES);
    attr_set = true;
  }
  void* kargs[] = {(void*)&wxt, (void*)&xT, (void*)&wh16, (void*)&wfc16,
                   (void*)&hbuf, (void*)&flags, (void*)&out};
  if (hipLaunchCooperativeKernel((const void*)bilstm_persist, dim3(256), dim3(512),
                                 kargs, SMEM_BYTES, stream) != hipSuccess) {
    // fallback: plain launch — 148 KB LDS forces 1 block/CU, 256 blocks on 256 CUs
    bilstm_persist<<<dim3(256), dim3(512), SMEM_BYTES, stream>>>(
        wxt, xT, wh16, wfc16, hbuf, flags, out);
  }
}